// Round 3
// baseline (758.143 us; speedup 1.0000x reference)
//
#include <hip/hip_runtime.h>
#include <math.h>

#define TSEQ 4096
#define DMODEL 768
#define NHEADS 12
#define DKH 64
#define DFF 3072
#define LOG2E 1.44269504f

typedef __attribute__((ext_vector_type(4))) float f32x4;
typedef __attribute__((ext_vector_type(8))) short s16x8;
typedef unsigned short u16;
typedef unsigned int u32;

__device__ __forceinline__ u16 f2bf(float x) {
    u32 u = __builtin_bit_cast(u32, x);
    u32 r = u + 0x7FFFu + ((u >> 16) & 1u);
    return (u16)(r >> 16);
}
__device__ __forceinline__ float bf2f(u16 h) {
    u32 u = ((u32)h) << 16;
    return __builtin_bit_cast(float, u);
}

__device__ __forceinline__ void gll16(const void* g, void* lds) {
    __builtin_amdgcn_global_load_lds(
        (const __attribute__((address_space(1))) u32*)g,
        (__attribute__((address_space(3))) u32*)lds, 16, 0, 0);
}

// ---------------------------------------------------------------------------
// x [4096][768] f32 -> x'' [4096][2304] bf16  (hi | hi | lo)
// ---------------------------------------------------------------------------
__global__ __launch_bounds__(256) void split_x_kernel(const float* __restrict__ in,
                                                      u16* __restrict__ out)
{
    int idx = blockIdx.x * 256 + threadIdx.x;
    for (int i = idx; i < 786432; i += 262144) {
        int row = i / 192;
        int c = (i - row * 192) << 2;
        float4 v = *(const float4*)(in + (size_t)row * DMODEL + c);
        u16 h0 = f2bf(v.x), h1 = f2bf(v.y), h2 = f2bf(v.z), h3 = f2bf(v.w);
        u16 l0 = f2bf(v.x - bf2f(h0)), l1 = f2bf(v.y - bf2f(h1));
        u16 l2 = f2bf(v.z - bf2f(h2)), l3 = f2bf(v.w - bf2f(h3));
        u16* o = out + (size_t)row * 2304 + c;
        ushort4 hv = make_ushort4(h0, h1, h2, h3);
        *(ushort4*)(o)        = hv;
        *(ushort4*)(o + 768)  = hv;
        *(ushort4*)(o + 1536) = make_ushort4(l0, l1, l2, l3);
    }
}

// ---------------------------------------------------------------------------
// W [K][N] f32 -> out[(nofs+n)][3K] bf16 rows = (Whi^T | Wlo^T | Whi^T)
// ---------------------------------------------------------------------------
__global__ __launch_bounds__(256) void wsplit(const float* __restrict__ W,
                                              u16* __restrict__ out,
                                              int K, int N, int nofs)
{
    __shared__ float t[32 * 33];
    const int tid = threadIdx.x;
    const int kt = blockIdx.y << 5, nt = blockIdx.x << 5;
    const int r = tid >> 3, c4 = tid & 7;
    float4 v = *(const float4*)(W + (size_t)(kt + r) * N + nt + (c4 << 2));
    t[r * 33 + (c4 << 2) + 0] = v.x;
    t[r * 33 + (c4 << 2) + 1] = v.y;
    t[r * 33 + (c4 << 2) + 2] = v.z;
    t[r * 33 + (c4 << 2) + 3] = v.w;
    __syncthreads();
    const int P3 = 3 * K;
    float a0 = t[((c4 << 2) + 0) * 33 + r];
    float a1 = t[((c4 << 2) + 1) * 33 + r];
    float a2 = t[((c4 << 2) + 2) * 33 + r];
    float a3 = t[((c4 << 2) + 3) * 33 + r];
    u16 h0 = f2bf(a0), h1 = f2bf(a1), h2 = f2bf(a2), h3 = f2bf(a3);
    u16 l0 = f2bf(a0 - bf2f(h0)), l1 = f2bf(a1 - bf2f(h1));
    u16 l2 = f2bf(a2 - bf2f(h2)), l3 = f2bf(a3 - bf2f(h3));
    u16* o = out + (size_t)(nofs + nt + r) * P3 + kt + (c4 << 2);
    ushort4 hv = make_ushort4(h0, h1, h2, h3);
    *(ushort4*)(o)         = hv;
    *(ushort4*)(o + K)     = make_ushort4(l0, l1, l2, l3);
    *(ushort4*)(o + 2 * K) = hv;
}

__global__ __launch_bounds__(256) void bias_cat_kernel(const float* bq, const float* bk,
                                                       const float* bv, float* o)
{
    int i = blockIdx.x * 256 + threadIdx.x;
    if (i < 768) o[i] = bq[i];
    else if (i < 1536) o[i] = bk[i - 768];
    else if (i < 2304) o[i] = bv[i - 1536];
}

// ---------------------------------------------------------------------------
// bf16 MFMA GEMM over split operands. A[M][KP], B^T[N][KP] bf16, KP = 3K.
// EPI 0: QKV (Q scaled by 0.125*log2e; K head-major; V^T)
// EPI 1: f32 out = acc + bias + R
// EPI 2: relu(acc+bias) -> split store (hi|hi|lo), pitch 3*SEG
// ---------------------------------------------------------------------------
template<int BM, int BN, int EPI>
__global__ __launch_bounds__(256) void gemm_bf3(
    const u16* __restrict__ A, const u16* __restrict__ B,
    const float* __restrict__ bias, const float* __restrict__ R,
    float* __restrict__ Cf, u16* __restrict__ Cs,
    u16* __restrict__ Qb, u16* __restrict__ Kb, u16* __restrict__ VTb,
    int N, int KP, int SEG)
{
    constexpr int FM = BM / 32, FN = BN / 32, NC = BN / 2, NCP = NC + 4;
    __shared__ u16 As[BM * 32];
    __shared__ u16 Bs[BN * 32];
    __shared__ float Ep[4 * 16 * NCP];

    const int tid = threadIdx.x;
    const int w = tid >> 6, lane = tid & 63;
    const int wr = w >> 1, wc = w & 1;
    const int m0 = blockIdx.y * BM, n0 = blockIdx.x * BN;
    const int li = lane & 15, g = lane >> 4;

    f32x4 acc[FM][FN];
#pragma unroll
    for (int mi = 0; mi < FM; ++mi)
#pragma unroll
        for (int ni = 0; ni < FN; ++ni) acc[mi][ni] = (f32x4){0.f, 0.f, 0.f, 0.f};

    const int srow = lane >> 2, sc = lane & 3;
    for (int k0 = 0; k0 < KP; k0 += 32) {
        __syncthreads();
#pragma unroll
        for (int i = 0; i < BM / 64; ++i) {
            int inst = w * (BM / 64) + i;
            const u16* gp = A + (size_t)(m0 + inst * 16 + srow) * KP + k0 + sc * 8;
            gll16(gp, &As[inst * 512]);
        }
#pragma unroll
        for (int i = 0; i < BN / 64; ++i) {
            int inst = w * (BN / 64) + i;
            const u16* gp = B + (size_t)(n0 + inst * 16 + srow) * KP + k0 + sc * 8;
            gll16(gp, &Bs[inst * 512]);
        }
        __syncthreads();
        s16x8 af[FM], bf[FN];
#pragma unroll
        for (int mi = 0; mi < FM; ++mi)
            af[mi] = *(const s16x8*)&As[(wr * (BM / 2) + mi * 16 + li) * 32 + g * 8];
#pragma unroll
        for (int ni = 0; ni < FN; ++ni)
            bf[ni] = *(const s16x8*)&Bs[(wc * (BN / 2) + ni * 16 + li) * 32 + g * 8];
#pragma unroll
        for (int mi = 0; mi < FM; ++mi)
#pragma unroll
            for (int ni = 0; ni < FN; ++ni)
                acc[mi][ni] = __builtin_amdgcn_mfma_f32_16x16x32_bf16(
                    af[mi], bf[ni], acc[mi][ni], 0, 0, 0);
    }
    __syncthreads();

    float* ep = Ep + w * 16 * NCP;
    const int colbase = n0 + wc * NC;
    const int rr = lane >> 2, ch = lane & 3;

#pragma unroll
    for (int mi = 0; mi < FM; ++mi) {
#pragma unroll
        for (int ni = 0; ni < FN; ++ni)
#pragma unroll
            for (int r = 0; r < 4; ++r)
                ep[(g * 4 + r) * NCP + ni * 16 + li] = acc[mi][ni][r];
        asm volatile("s_waitcnt lgkmcnt(0)" ::: "memory");

        const int grow0 = m0 + wr * (BM / 2) + mi * 16;
        const int grow = grow0 + rr;

        if constexpr (EPI == 1) {
#pragma unroll
            for (int q = 0; q < NC / 16; ++q) {
                int col = ch * (NC / 4) + q * 4;
                f32x4 v = *(f32x4*)&ep[rr * NCP + col];
                int gn = colbase + col;
                float4 bb = *(const float4*)(bias + gn);
                float4 rv = *(const float4*)(R + (size_t)grow * N + gn);
                float4 ov;
                ov.x = v[0] + bb.x + rv.x; ov.y = v[1] + bb.y + rv.y;
                ov.z = v[2] + bb.z + rv.z; ov.w = v[3] + bb.w + rv.w;
                *(float4*)(Cf + (size_t)grow * N + gn) = ov;
            }
        } else if constexpr (EPI == 2) {
#pragma unroll
            for (int q = 0; q < NC / 16; ++q) {
                int col = ch * (NC / 4) + q * 4;
                f32x4 v = *(f32x4*)&ep[rr * NCP + col];
                int gn = colbase + col;
                float4 bb = *(const float4*)(bias + gn);
                float x0 = fmaxf(v[0] + bb.x, 0.f), x1 = fmaxf(v[1] + bb.y, 0.f);
                float x2 = fmaxf(v[2] + bb.z, 0.f), x3 = fmaxf(v[3] + bb.w, 0.f);
                u16 h0 = f2bf(x0), h1 = f2bf(x1), h2 = f2bf(x2), h3 = f2bf(x3);
                u16 l0 = f2bf(x0 - bf2f(h0)), l1 = f2bf(x1 - bf2f(h1));
                u16 l2 = f2bf(x2 - bf2f(h2)), l3 = f2bf(x3 - bf2f(h3));
                u16* o = Cs + (size_t)grow * (3 * SEG) + gn;
                ushort4 hv = make_ushort4(h0, h1, h2, h3);
                *(ushort4*)(o)           = hv;
                *(ushort4*)(o + SEG)     = hv;
                *(ushort4*)(o + 2 * SEG) = make_ushort4(l0, l1, l2, l3);
            }
        } else {  // EPI 0: QKV
            const int seg = colbase / 768;
            const int hh = (colbase % 768) >> 6;
            if (seg < 2) {
                u16* dst = (seg == 0) ? Qb : Kb;
                const float sc2 = (seg == 0) ? 0.125f * LOG2E : 1.0f;
#pragma unroll
                for (int q = 0; q < NC / 16; ++q) {
                    int col = ch * (NC / 4) + q * 4;
                    f32x4 v = *(f32x4*)&ep[rr * NCP + col];
                    float4 bb = *(const float4*)(bias + colbase + col);
                    u16 h0 = f2bf((v[0] + bb.x) * sc2);
                    u16 h1 = f2bf((v[1] + bb.y) * sc2);
                    u16 h2 = f2bf((v[2] + bb.z) * sc2);
                    u16 h3 = f2bf((v[3] + bb.w) * sc2);
                    *(ushort4*)&dst[((size_t)(hh << 12) + grow) * 64 + col] =
                        make_ushort4(h0, h1, h2, h3);
                }
            } else {
                float bb = bias[colbase + lane];
                s16x8 pa, pb;
#pragma unroll
                for (int r2 = 0; r2 < 8; ++r2)
                    pa[r2] = (short)f2bf(ep[r2 * NCP + lane] + bb);
#pragma unroll
                for (int r2 = 0; r2 < 8; ++r2)
                    pb[r2] = (short)f2bf(ep[(8 + r2) * NCP + lane] + bb);
                u16* ov = VTb + ((size_t)(hh << 6) + lane) * TSEQ + grow0;
                *(s16x8*)(ov)     = pa;
                *(s16x8*)(ov + 8) = pb;
            }
        }
    }
}

// ---------------------------------------------------------------------------
// Flash attention, bf16 MFMA, causal. Block = 128 q-rows x 1 head, 4 waves
// (32 q/wave). Swapped QK^T (S^T = K·Q^T) -> per-lane rows, in-lane softmax
// reductions. Double-buffered K/V via global_load_lds with pre-swizzled
// source (linear LDS dest), 1 barrier per k-tile. Defer-max (THR=8, log2
// domain; Q prescaled by 0.125*log2e at QKV). Output: ctx'' split bf16.
// ---------------------------------------------------------------------------
__global__ __launch_bounds__(256) void attn128(
    const u16* __restrict__ Qb, const u16* __restrict__ Kb,
    const u16* __restrict__ VTb, u16* __restrict__ ctxs)
{
    __shared__ u16 Ks[2][4096];   // [64 tok][64 d], 8-col-block XOR swizzle
    __shared__ u16 Vs[2][4096];   // V^T [64 d][64 tok], same swizzle
    __shared__ u16 Ps[4][2048];   // per-wave P [32 q][64 k], swizzled

    const int tid = threadIdx.x, w = tid >> 6, lane = tid & 63;
    const int g = lane >> 4, li = lane & 15, l7 = lane & 7;
    const int qbk = 31 - (int)blockIdx.x;     // heavy blocks first
    const int h = blockIdx.y;
    const int q0 = qbk << 7;
    const int nkb = 2 * qbk + 2;

    const u16* Qh = Qb + ((size_t)h << 18);
    const u16* Kh = Kb + ((size_t)h << 18);
    const u16* Vh = VTb + ((size_t)h << 18);

    s16x8 qf[2][2];
#pragma unroll
    for (int b = 0; b < 2; ++b)
#pragma unroll
        for (int dc = 0; dc < 2; ++dc)
            qf[b][dc] = *(const s16x8*)(Qh +
                (size_t)(q0 + w * 32 + b * 16 + li) * 64 + dc * 32 + g * 8);

    f32x4 o[2][4];
    float m_[2], l_[2];
#pragma unroll
    for (int b = 0; b < 2; ++b) {
        m_[b] = -1e30f; l_[b] = 0.f;
#pragma unroll
        for (int d16 = 0; d16 < 4; ++d16) o[b][d16] = (f32x4){0.f, 0.f, 0.f, 0.f};
    }

    const int srow8 = lane >> 3, scb8 = lane & 7;
    // prologue: stage tile 0 into buffer 0
#pragma unroll
    for (int i = 0; i < 2; ++i) {
        int lbase = i * 256 + w * 64;
        int row = (lbase >> 3) + srow8;
        int c8 = scb8 ^ (row & 7);
        gll16(Kh + (size_t)row * 64 + c8 * 8, &Ks[0][lbase * 8]);
        gll16(Vh + (size_t)row * TSEQ + c8 * 8, &Vs[0][lbase * 8]);
    }
    __syncthreads();

    for (int kb = 0; kb < nkb; ++kb) {
        const int cur = kb & 1;
        if (kb + 1 < nkb) {   // prefetch next tile into other buffer
            const int kn = kb + 1;
#pragma unroll
            for (int i = 0; i < 2; ++i) {
                int lbase = i * 256 + w * 64;
                int row = (lbase >> 3) + srow8;
                int c8 = scb8 ^ (row & 7);
                gll16(Kh + (size_t)((kn << 6) + row) * 64 + c8 * 8, &Ks[cur ^ 1][lbase * 8]);
                gll16(Vh + (size_t)row * TSEQ + (kn << 6) + c8 * 8, &Vs[cur ^ 1][lbase * 8]);
            }
        }

        // QK^T (swapped): s[c][b] = K-chunk-c · Q-frag-b  -> S^T[k][q]
        f32x4 s[4][2];
#pragma unroll
        for (int c = 0; c < 4; ++c) {
#pragma unroll
            for (int b = 0; b < 2; ++b) s[c][b] = (f32x4){0.f, 0.f, 0.f, 0.f};
            s16x8 a0 = *(const s16x8*)&Ks[cur][(c * 16 + li) * 64 + ((g * 8) ^ (l7 << 3))];
            s16x8 a1 = *(const s16x8*)&Ks[cur][(c * 16 + li) * 64 + ((32 + g * 8) ^ (l7 << 3))];
#pragma unroll
            for (int b = 0; b < 2; ++b) {
                s[c][b] = __builtin_amdgcn_mfma_f32_16x16x32_bf16(a0, qf[b][0], s[c][b], 0, 0, 0);
                s[c][b] = __builtin_amdgcn_mfma_f32_16x16x32_bf16(a1, qf[b][1], s[c][b], 0, 0, 0);
            }
        }

        // causal mask (only the last two tiles can touch the diagonal)
        if (kb >= (q0 >> 6)) {
#pragma unroll
            for (int c = 0; c < 4; ++c)
#pragma unroll
                for (int b = 0; b < 2; ++b)
#pragma unroll
                    for (int r = 0; r < 4; ++r) {
                        int kglob = (kb << 6) + c * 16 + g * 4 + r;
                        int qglob = q0 + w * 32 + b * 16 + li;
                        if (kglob > qglob) s[c][b][r] = -1e30f;
                    }
        }

        // per-lane row softmax (row q = b*16+li), log2 domain
        float pm[2];
#pragma unroll
        for (int b = 0; b < 2; ++b) {
            float v0 = fmaxf(fmaxf(s[0][b][0], s[0][b][1]), fmaxf(s[0][b][2], s[0][b][3]));
            float v1 = fmaxf(fmaxf(s[1][b][0], s[1][b][1]), fmaxf(s[1][b][2], s[1][b][3]));
            float v2 = fmaxf(fmaxf(s[2][b][0], s[2][b][1]), fmaxf(s[2][b][2], s[2][b][3]));
            float v3 = fmaxf(fmaxf(s[3][b][0], s[3][b][1]), fmaxf(s[3][b][2], s[3][b][3]));
            float v = fmaxf(fmaxf(v0, v1), fmaxf(v2, v3));
            v = fmaxf(v, __shfl_xor(v, 16, 64));
            v = fmaxf(v, __shfl_xor(v, 32, 64));
            pm[b] = v;
        }
        int ok = (pm[0] <= m_[0] + 8.f) && (pm[1] <= m_[1] + 8.f);
        if (!__all(ok)) {       // rescale path (rare after warm-up)
            float scb[2];
#pragma unroll
            for (int b = 0; b < 2; ++b) {
                float mn = fmaxf(m_[b], pm[b]);
                scb[b] = exp2f(m_[b] - mn);
                m_[b] = mn;
                l_[b] *= scb[b];
            }
#pragma unroll
            for (int b = 0; b < 2; ++b)
#pragma unroll
                for (int r = 0; r < 4; ++r) {
                    float os = __shfl(scb[b], g * 4 + r, 64);
#pragma unroll
                    for (int d16 = 0; d16 < 4; ++d16) o[b][d16][r] *= os;
                }
        }
#pragma unroll
        for (int b = 0; b < 2; ++b) {
            float rsum = 0.f;
#pragma unroll
            for (int c = 0; c < 4; ++c) {
                float e0 = exp2f(s[c][b][0] - m_[b]);
                float e1 = exp2f(s[c][b][1] - m_[b]);
                float e2 = exp2f(s[c][b][2] - m_[b]);
                float e3 = exp2f(s[c][b][3] - m_[b]);
                rsum += (e0 + e1) + (e2 + e3);
                ushort4 pk = make_ushort4(f2bf(e0), f2bf(e1), f2bf(e2), f2bf(e3));
                *(ushort4*)&Ps[w][(b * 16 + li) * 64 + ((c * 16 + 4 * g) ^ (l7 << 3))] = pk;
            }
            rsum += __shfl_xor(rsum, 16, 64);
            rsum += __shfl_xor(rsum, 32, 64);
            l_[b] += rsum;
        }
        asm volatile("s_waitcnt lgkmcnt(0)" ::: "memory");
        __builtin_amdgcn_sched_barrier(0);

        // PV: O += P · V
#pragma unroll
        for (int ks = 0; ks < 2; ++ks) {
            int koff = (ks * 32 + g * 8) ^ (l7 << 3);
            s16x8 pf0 = *(const s16x8*)&Ps[w][li * 64 + koff];
            s16x8 pf1 = *(const s16x8*)&Ps[w][(16 + li) * 64 + koff];
#pragma unroll
            for (int d16 = 0; d16 < 4; ++d16) {
                s16x8 vf = *(const s16x8*)&Vs[cur][(d16 * 16 + li) * 64 + koff];
                o[0][d16] = __builtin_amdgcn_mfma_f32_16x16x32_bf16(pf0, vf, o[0][d16], 0, 0, 0);
                o[1][d16] = __builtin_amdgcn_mfma_f32_16x16x32_bf16(pf1, vf, o[1][d16], 0, 0, 0);
            }
        }
        __syncthreads();   // all waves done with buf[cur]; prefetch glls drained
    }

    // epilogue: normalize and write ctx'' split (hi|hi|lo)
#pragma unroll
    for (int b = 0; b < 2; ++b) {
        float il = 1.0f / l_[b];
#pragma unroll
        for (int r = 0; r < 4; ++r) {
            float iv = __shfl(il, g * 4 + r, 64);
            int qrow = q0 + w * 32 + b * 16 + g * 4 + r;
#pragma unroll
            for (int d16 = 0; d16 < 4; ++d16) {
                float v = o[b][d16][r] * iv;
                u16 hi = f2bf(v);
                u16 lo = f2bf(v - bf2f(hi));
                int col = (h << 6) + d16 * 16 + li;
                u16* o2 = ctxs + (size_t)qrow * 2304 + col;
                o2[0] = hi; o2[768] = hi; o2[1536] = lo;
            }
        }
    }
}

// ---------------------------------------------------------------------------
// LayerNorm over 768. SPLIT=1 also emits bf16 split (hi|hi|lo) operand.
// ---------------------------------------------------------------------------
template<int SPLIT>
__global__ __launch_bounds__(256) void ln_kernel(const float* __restrict__ in,
    const float* __restrict__ gw, const float* __restrict__ bw,
    float* __restrict__ outf, u16* __restrict__ outs)
{
    __shared__ float red[8];
    const int row = blockIdx.x, tid = threadIdx.x;
    const float* x = in + (size_t)row * DMODEL;
    float v0 = x[tid], v1 = x[tid + 256], v2 = x[tid + 512];
    float s = v0 + v1 + v2;
#pragma unroll
    for (int off = 32; off > 0; off >>= 1) s += __shfl_xor(s, off, 64);
    const int wv = tid >> 6, lane = tid & 63;
    if (lane == 0) red[wv] = s;
    __syncthreads();
    float mu = (red[0] + red[1] + red[2] + red[3]) * (1.0f / DMODEL);
    float d0 = v0 - mu, d1 = v1 - mu, d2 = v2 - mu;
    float s2 = d0 * d0 + d1 * d1 + d2 * d2;
#pragma unroll
    for (int off = 32; off > 0; off >>= 1) s2 += __shfl_xor(s2, off, 64);
    if (lane == 0) red[4 + wv] = s2;
    __syncthreads();
    float var = (red[4] + red[5] + red[6] + red[7]) * (1.0f / DMODEL);
    float rstd = rsqrtf(var + 1e-5f);
    float y0 = d0 * rstd * gw[tid] + bw[tid];
    float y1 = d1 * rstd * gw[tid + 256] + bw[tid + 256];
    float y2 = d2 * rstd * gw[tid + 512] + bw[tid + 512];
    float* yo = outf + (size_t)row * DMODEL;
    yo[tid] = y0; yo[tid + 256] = y1; yo[tid + 512] = y2;
    if constexpr (SPLIT) {
        u16* o = outs + (size_t)row * 2304;
        u16 h0 = f2bf(y0), h1 = f2bf(y1), h2 = f2bf(y2);
        o[tid] = h0;       o[768 + tid] = h0;       o[1536 + tid] = f2bf(y0 - bf2f(h0));
        o[tid + 256] = h1; o[1024 + tid] = h1;      o[1792 + tid] = f2bf(y1 - bf2f(h1));
        o[tid + 512] = h2; o[1280 + tid] = h2;      o[2048 + tid] = f2bf(y2 - bf2f(h2));
    }
}

// ---------------------------------------------------------------------------
extern "C" void kernel_launch(void* const* d_in, const int* in_sizes, int n_in,
                              void* d_out, int out_size, void* d_ws, size_t ws_size,
                              hipStream_t stream)
{
    const float* x  = (const float*)d_in[0];
    const float* Wq = (const float*)d_in[1];  const float* bq = (const float*)d_in[2];
    const float* Wk = (const float*)d_in[3];  const float* bk = (const float*)d_in[4];
    const float* Wv = (const float*)d_in[5];  const float* bv = (const float*)d_in[6];
    const float* Wo = (const float*)d_in[7];  const float* bo = (const float*)d_in[8];
    const float* W1 = (const float*)d_in[9];  const float* b1 = (const float*)d_in[10];
    const float* W2 = (const float*)d_in[11]; const float* b2 = (const float*)d_in[12];
    const float* g1 = (const float*)d_in[13]; const float* be1 = (const float*)d_in[14];
    const float* g2 = (const float*)d_in[15]; const float* be2 = (const float*)d_in[16];
    float* out = (float*)d_out;

    char* wsb = (char*)d_ws;
    u16*   xs    = (u16*)(wsb + 0);
    u16*   Qb    = (u16*)(wsb + 18874368);
    u16*   Kb2   = (u16*)(wsb + 25165824);
    u16*   VTb   = (u16*)(wsb + 31457280);
    u16*   ctxs  = (u16*)(wsb + 37748736);
    u16*   Wqkvs = (u16*)(wsb + 56623104);
    u16*   Wos   = (u16*)(wsb + 67239936);
    float* bcat  = (float*)(wsb + 70778880);
    float* s1    = (float*)(wsb + 70788096);
    u16*   ff1s  = (u16*)(wsb + 0);
    u16*   W1s   = (u16*)(wsb + 83371008);
    u16*   W2s   = (u16*)(wsb + 97526784);
    float* h     = (float*)(wsb + 111682560);
    u16*   hs    = (u16*)(wsb + 124265472);
    float* t2    = (float*)(wsb + 143139840);

    split_x_kernel<<<1024, 256, 0, stream>>>(x, xs);
    wsplit<<<dim3(24, 24), 256, 0, stream>>>(Wq, Wqkvs, 768, 768, 0);
    wsplit<<<dim3(24, 24), 256, 0, stream>>>(Wk, Wqkvs, 768, 768, 768);
    wsplit<<<dim3(24, 24), 256, 0, stream>>>(Wv, Wqkvs, 768, 768, 1536);
    wsplit<<<dim3(24, 24), 256, 0, stream>>>(Wo, Wos, 768, 768, 0);
    wsplit<<<dim3(96, 24), 256, 0, stream>>>(W1, W1s, 768, 3072, 0);
    wsplit<<<dim3(24, 96), 256, 0, stream>>>(W2, W2s, 3072, 768, 0);
    bias_cat_kernel<<<9, 256, 0, stream>>>(bq, bk, bv, bcat);

    gemm_bf3<128, 128, 0><<<dim3(18, 32), 256, 0, stream>>>(
        xs, Wqkvs, bcat, nullptr, nullptr, nullptr, Qb, Kb2, VTb, 2304, 2304, 0);
    attn128<<<dim3(32, 12), 256, 0, stream>>>(Qb, Kb2, VTb, ctxs);
    gemm_bf3<128, 128, 1><<<dim3(6, 32), 256, 0, stream>>>(
        ctxs, Wos, bo, x, s1, nullptr, nullptr, nullptr, nullptr, 768, 2304, 0);
    ln_kernel<1><<<4096, 256, 0, stream>>>(s1, g1, be1, h, hs);
    gemm_bf3<128, 128, 2><<<dim3(24, 32), 256, 0, stream>>>(
        hs, W1s, b1, nullptr, nullptr, ff1s, nullptr, nullptr, nullptr, 3072, 2304, 3072);
    gemm_bf3<128, 128, 1><<<dim3(6, 32), 256, 0, stream>>>(
        ff1s, W2s, b2, h, t2, nullptr, nullptr, nullptr, nullptr, 768, 9216, 0);
    ln_kernel<0><<<4096, 256, 0, stream>>>(t2, g2, be2, out, nullptr);
}

// Round 4
// 445.626 us; speedup vs baseline: 1.7013x; 1.7013x over previous
//
#include <hip/hip_runtime.h>
#include <math.h>

#define TSEQ 4096
#define DMODEL 768
#define NHEADS 12
#define DKH 64
#define DFF 3072
#define LOG2E 1.44269504f

typedef __attribute__((ext_vector_type(4))) float f32x4;
typedef __attribute__((ext_vector_type(8))) short s16x8;
typedef unsigned short u16;
typedef unsigned int u32;

__device__ __forceinline__ u16 f2bf(float x) {
    u32 u = __builtin_bit_cast(u32, x);
    u32 r = u + 0x7FFFu + ((u >> 16) & 1u);
    return (u16)(r >> 16);
}
__device__ __forceinline__ float bf2f(u16 h) {
    u32 u = ((u32)h) << 16;
    return __builtin_bit_cast(float, u);
}

__device__ __forceinline__ void gll16(const void* g, void* lds) {
    __builtin_amdgcn_global_load_lds(
        (const __attribute__((address_space(1))) u32*)g,
        (__attribute__((address_space(3))) u32*)lds, 16, 0, 0);
}

// ---------------------------------------------------------------------------
// f32 -> bf16 cast, vectorized. n4 = count of float4 chunks.
// ---------------------------------------------------------------------------
__global__ __launch_bounds__(256) void tobf16(const float* __restrict__ in,
                                              u16* __restrict__ out, int n4)
{
    int idx = blockIdx.x * 256 + threadIdx.x;
    for (int i = idx; i < n4; i += 262144) {
        float4 v = *(const float4*)(in + (size_t)i * 4);
        *(ushort4*)(out + (size_t)i * 4) =
            make_ushort4(f2bf(v.x), f2bf(v.y), f2bf(v.z), f2bf(v.w));
    }
}

// ---------------------------------------------------------------------------
// W [K][N] f32 -> out[(nofs+n)][K] bf16 (transposed, single precision level)
// grid (N/32, K/32), 256 threads, 32x32 LDS transpose tile.
// ---------------------------------------------------------------------------
__global__ __launch_bounds__(256) void wtrans(const float* __restrict__ W,
                                              u16* __restrict__ out,
                                              int K, int N, int nofs)
{
    __shared__ float t[32 * 33];
    const int tid = threadIdx.x;
    const int kt = blockIdx.y << 5, nt = blockIdx.x << 5;
    const int r = tid >> 3, c4 = tid & 7;
    float4 v = *(const float4*)(W + (size_t)(kt + r) * N + nt + (c4 << 2));
    t[r * 33 + (c4 << 2) + 0] = v.x;
    t[r * 33 + (c4 << 2) + 1] = v.y;
    t[r * 33 + (c4 << 2) + 2] = v.z;
    t[r * 33 + (c4 << 2) + 3] = v.w;
    __syncthreads();
    float a0 = t[((c4 << 2) + 0) * 33 + r];
    float a1 = t[((c4 << 2) + 1) * 33 + r];
    float a2 = t[((c4 << 2) + 2) * 33 + r];
    float a3 = t[((c4 << 2) + 3) * 33 + r];
    u16* o = out + (size_t)(nofs + nt + r) * K + kt + (c4 << 2);
    *(ushort4*)o = make_ushort4(f2bf(a0), f2bf(a1), f2bf(a2), f2bf(a3));
}

__global__ __launch_bounds__(256) void bias_cat_kernel(const float* bq, const float* bk,
                                                       const float* bv, float* o)
{
    int i = blockIdx.x * 256 + threadIdx.x;
    if (i < 768) o[i] = bq[i];
    else if (i < 1536) o[i] = bk[i - 768];
    else if (i < 2304) o[i] = bv[i - 1536];
}

// ---------------------------------------------------------------------------
// bf16 MFMA GEMM. A[M][KP], B^T[N][KP] bf16. BK=32, 4 waves.
// LDS XOR-swizzled (pre-swizzled global source + swizzled read -> 2-way max).
// XCD-bijective block remap (requires nwg % 8 == 0).
// EPI 0: QKV (Q scaled by 0.125*log2e; Q/K head-major bf16; V^T bf16)
// EPI 1: f32 out = acc + bias + R
// EPI 2: relu(acc+bias) -> bf16 store, pitch N
// ---------------------------------------------------------------------------
template<int BM, int BN, int EPI>
__global__ __launch_bounds__(256) void gemm_bf(
    const u16* __restrict__ A, const u16* __restrict__ B,
    const float* __restrict__ bias, const float* __restrict__ R,
    float* __restrict__ Cf, u16* __restrict__ Cs,
    u16* __restrict__ Qb, u16* __restrict__ Kb, u16* __restrict__ VTb,
    int N, int KP)
{
    constexpr int FM = BM / 32, FN = BN / 32, NC = BN / 2, NCP = NC + 4;
    __shared__ u16 As[BM * 32];
    __shared__ u16 Bs[BN * 32];
    __shared__ float Ep[4 * 16 * NCP];

    const int tid = threadIdx.x;
    const int w = tid >> 6, lane = tid & 63;
    const int wr = w >> 1, wc = w & 1;
    const int li = lane & 15, g = lane >> 4;

    // XCD-aware bijective remap: consecutive logical ids (n fastest) per XCD.
    const int gX = gridDim.x;
    const int nwg = gridDim.x * gridDim.y;
    const int wid = blockIdx.y * gX + blockIdx.x;
    const int qc = nwg >> 3;          // nwg % 8 == 0 for all our grids
    const int nid = (wid & 7) * qc + (wid >> 3);
    const int m0 = (nid / gX) * BM, n0 = (nid % gX) * BN;

    f32x4 acc[FM][FN];
#pragma unroll
    for (int mi = 0; mi < FM; ++mi)
#pragma unroll
        for (int ni = 0; ni < FN; ++ni) acc[mi][ni] = (f32x4){0.f, 0.f, 0.f, 0.f};

    const int srow = lane >> 2;
    const int scs = (lane & 3) ^ ((srow >> 1) & 3);   // swizzled k-slot source
    for (int k0 = 0; k0 < KP; k0 += 32) {
        __syncthreads();
#pragma unroll
        for (int i = 0; i < BM / 64; ++i) {
            int inst = w * (BM / 64) + i;
            const u16* gp = A + (size_t)(m0 + inst * 16 + srow) * KP + k0 + scs * 8;
            gll16(gp, &As[inst * 512]);
        }
#pragma unroll
        for (int i = 0; i < BN / 64; ++i) {
            int inst = w * (BN / 64) + i;
            const u16* gp = B + (size_t)(n0 + inst * 16 + srow) * KP + k0 + scs * 8;
            gll16(gp, &Bs[inst * 512]);
        }
        __syncthreads();
        s16x8 af[FM], bfr[FN];
#pragma unroll
        for (int mi = 0; mi < FM; ++mi) {
            int Ra = wr * (BM / 2) + mi * 16 + li;
            af[mi] = *(const s16x8*)&As[Ra * 32 + ((g ^ ((Ra >> 1) & 3)) << 3)];
        }
#pragma unroll
        for (int ni = 0; ni < FN; ++ni) {
            int Rb = wc * (BN / 2) + ni * 16 + li;
            bfr[ni] = *(const s16x8*)&Bs[Rb * 32 + ((g ^ ((Rb >> 1) & 3)) << 3)];
        }
        __builtin_amdgcn_s_setprio(1);
#pragma unroll
        for (int mi = 0; mi < FM; ++mi)
#pragma unroll
            for (int ni = 0; ni < FN; ++ni)
                acc[mi][ni] = __builtin_amdgcn_mfma_f32_16x16x32_bf16(
                    af[mi], bfr[ni], acc[mi][ni], 0, 0, 0);
        __builtin_amdgcn_s_setprio(0);
    }
    __syncthreads();

    float* ep = Ep + w * 16 * NCP;
    const int colbase = n0 + wc * NC;
    const int rr = lane >> 2, ch = lane & 3;

#pragma unroll
    for (int mi = 0; mi < FM; ++mi) {
#pragma unroll
        for (int ni = 0; ni < FN; ++ni)
#pragma unroll
            for (int r = 0; r < 4; ++r)
                ep[(g * 4 + r) * NCP + ni * 16 + li] = acc[mi][ni][r];
        asm volatile("s_waitcnt lgkmcnt(0)" ::: "memory");

        const int grow0 = m0 + wr * (BM / 2) + mi * 16;
        const int grow = grow0 + rr;

        if constexpr (EPI == 1) {
#pragma unroll
            for (int q = 0; q < NC / 16; ++q) {
                int col = ch * (NC / 4) + q * 4;
                f32x4 v = *(f32x4*)&ep[rr * NCP + col];
                int gn = colbase + col;
                float4 bb = *(const float4*)(bias + gn);
                float4 rv = *(const float4*)(R + (size_t)grow * N + gn);
                float4 ov;
                ov.x = v[0] + bb.x + rv.x; ov.y = v[1] + bb.y + rv.y;
                ov.z = v[2] + bb.z + rv.z; ov.w = v[3] + bb.w + rv.w;
                *(float4*)(Cf + (size_t)grow * N + gn) = ov;
            }
        } else if constexpr (EPI == 2) {
#pragma unroll
            for (int q = 0; q < NC / 16; ++q) {
                int col = ch * (NC / 4) + q * 4;
                f32x4 v = *(f32x4*)&ep[rr * NCP + col];
                int gn = colbase + col;
                float4 bb = *(const float4*)(bias + gn);
                float x0 = fmaxf(v[0] + bb.x, 0.f), x1 = fmaxf(v[1] + bb.y, 0.f);
                float x2 = fmaxf(v[2] + bb.z, 0.f), x3 = fmaxf(v[3] + bb.w, 0.f);
                *(ushort4*)(Cs + (size_t)grow * N + gn) =
                    make_ushort4(f2bf(x0), f2bf(x1), f2bf(x2), f2bf(x3));
            }
        } else {  // EPI 0: QKV
            const int seg = colbase / 768;
            const int hh = (colbase % 768) >> 6;
            if (seg < 2) {
                u16* dst = (seg == 0) ? Qb : Kb;
                const float sc2 = (seg == 0) ? 0.125f * LOG2E : 1.0f;
#pragma unroll
                for (int q = 0; q < NC / 16; ++q) {
                    int col = ch * (NC / 4) + q * 4;
                    f32x4 v = *(f32x4*)&ep[rr * NCP + col];
                    float4 bb = *(const float4*)(bias + colbase + col);
                    u16 h0 = f2bf((v[0] + bb.x) * sc2);
                    u16 h1 = f2bf((v[1] + bb.y) * sc2);
                    u16 h2 = f2bf((v[2] + bb.z) * sc2);
                    u16 h3 = f2bf((v[3] + bb.w) * sc2);
                    *(ushort4*)&dst[((size_t)(hh << 12) + grow) * 64 + col] =
                        make_ushort4(h0, h1, h2, h3);
                }
            } else {
                float bb = bias[colbase + lane];
                s16x8 pa, pb;
#pragma unroll
                for (int r2 = 0; r2 < 8; ++r2)
                    pa[r2] = (short)f2bf(ep[r2 * NCP + lane] + bb);
#pragma unroll
                for (int r2 = 0; r2 < 8; ++r2)
                    pb[r2] = (short)f2bf(ep[(8 + r2) * NCP + lane] + bb);
                u16* ov = VTb + ((size_t)(hh << 6) + lane) * TSEQ + grow0;
                *(s16x8*)(ov)     = pa;
                *(s16x8*)(ov + 8) = pb;
            }
        }
    }
}

// ---------------------------------------------------------------------------
// Flash attention, bf16 MFMA, causal. Block = 128 q-rows x 1 head, 4 waves.
// Swapped QK^T, in-lane softmax, double-buffered K/V via global_load_lds
// (pre-swizzled source), defer-max (THR=8, log2 domain). ctx out: bf16.
// ---------------------------------------------------------------------------
__global__ __launch_bounds__(256) void attn128(
    const u16* __restrict__ Qb, const u16* __restrict__ Kb,
    const u16* __restrict__ VTb, u16* __restrict__ ctxb)
{
    __shared__ u16 Ks[2][4096];
    __shared__ u16 Vs[2][4096];
    __shared__ u16 Ps[4][2048];

    const int tid = threadIdx.x, w = tid >> 6, lane = tid & 63;
    const int g = lane >> 4, li = lane & 15, l7 = lane & 7;
    const int qbk = 31 - (int)blockIdx.x;
    const int h = blockIdx.y;
    const int q0 = qbk << 7;
    const int nkb = 2 * qbk + 2;

    const u16* Qh = Qb + ((size_t)h << 18);
    const u16* Kh = Kb + ((size_t)h << 18);
    const u16* Vh = VTb + ((size_t)h << 18);

    s16x8 qf[2][2];
#pragma unroll
    for (int b = 0; b < 2; ++b)
#pragma unroll
        for (int dc = 0; dc < 2; ++dc)
            qf[b][dc] = *(const s16x8*)(Qh +
                (size_t)(q0 + w * 32 + b * 16 + li) * 64 + dc * 32 + g * 8);

    f32x4 o[2][4];
    float m_[2], l_[2];
#pragma unroll
    for (int b = 0; b < 2; ++b) {
        m_[b] = -1e30f; l_[b] = 0.f;
#pragma unroll
        for (int d16 = 0; d16 < 4; ++d16) o[b][d16] = (f32x4){0.f, 0.f, 0.f, 0.f};
    }

    const int srow8 = lane >> 3, scb8 = lane & 7;
#pragma unroll
    for (int i = 0; i < 2; ++i) {
        int lbase = i * 256 + w * 64;
        int row = (lbase >> 3) + srow8;
        int c8 = scb8 ^ (row & 7);
        gll16(Kh + (size_t)row * 64 + c8 * 8, &Ks[0][lbase * 8]);
        gll16(Vh + (size_t)row * TSEQ + c8 * 8, &Vs[0][lbase * 8]);
    }
    __syncthreads();

    for (int kb = 0; kb < nkb; ++kb) {
        const int cur = kb & 1;
        if (kb + 1 < nkb) {
            const int kn = kb + 1;
#pragma unroll
            for (int i = 0; i < 2; ++i) {
                int lbase = i * 256 + w * 64;
                int row = (lbase >> 3) + srow8;
                int c8 = scb8 ^ (row & 7);
                gll16(Kh + (size_t)((kn << 6) + row) * 64 + c8 * 8, &Ks[cur ^ 1][lbase * 8]);
                gll16(Vh + (size_t)row * TSEQ + (kn << 6) + c8 * 8, &Vs[cur ^ 1][lbase * 8]);
            }
        }

        f32x4 s[4][2];
        __builtin_amdgcn_s_setprio(1);
#pragma unroll
        for (int c = 0; c < 4; ++c) {
#pragma unroll
            for (int b = 0; b < 2; ++b) s[c][b] = (f32x4){0.f, 0.f, 0.f, 0.f};
            s16x8 a0 = *(const s16x8*)&Ks[cur][(c * 16 + li) * 64 + ((g * 8) ^ (l7 << 3))];
            s16x8 a1 = *(const s16x8*)&Ks[cur][(c * 16 + li) * 64 + ((32 + g * 8) ^ (l7 << 3))];
#pragma unroll
            for (int b = 0; b < 2; ++b) {
                s[c][b] = __builtin_amdgcn_mfma_f32_16x16x32_bf16(a0, qf[b][0], s[c][b], 0, 0, 0);
                s[c][b] = __builtin_amdgcn_mfma_f32_16x16x32_bf16(a1, qf[b][1], s[c][b], 0, 0, 0);
            }
        }
        __builtin_amdgcn_s_setprio(0);

        if (kb >= (q0 >> 6)) {
#pragma unroll
            for (int c = 0; c < 4; ++c)
#pragma unroll
                for (int b = 0; b < 2; ++b)
#pragma unroll
                    for (int r = 0; r < 4; ++r) {
                        int kglob = (kb << 6) + c * 16 + g * 4 + r;
                        int qglob = q0 + w * 32 + b * 16 + li;
                        if (kglob > qglob) s[c][b][r] = -1e30f;
                    }
        }

        float pm[2];
#pragma unroll
        for (int b = 0; b < 2; ++b) {
            float v0 = fmaxf(fmaxf(s[0][b][0], s[0][b][1]), fmaxf(s[0][b][2], s[0][b][3]));
            float v1 = fmaxf(fmaxf(s[1][b][0], s[1][b][1]), fmaxf(s[1][b][2], s[1][b][3]));
            float v2 = fmaxf(fmaxf(s[2][b][0], s[2][b][1]), fmaxf(s[2][b][2], s[2][b][3]));
            float v3 = fmaxf(fmaxf(s[3][b][0], s[3][b][1]), fmaxf(s[3][b][2], s[3][b][3]));
            float v = fmaxf(fmaxf(v0, v1), fmaxf(v2, v3));
            v = fmaxf(v, __shfl_xor(v, 16, 64));
            v = fmaxf(v, __shfl_xor(v, 32, 64));
            pm[b] = v;
        }
        int ok = (pm[0] <= m_[0] + 8.f) && (pm[1] <= m_[1] + 8.f);
        if (!__all(ok)) {
            float scb[2];
#pragma unroll
            for (int b = 0; b < 2; ++b) {
                float mn = fmaxf(m_[b], pm[b]);
                scb[b] = exp2f(m_[b] - mn);
                m_[b] = mn;
                l_[b] *= scb[b];
            }
#pragma unroll
            for (int b = 0; b < 2; ++b)
#pragma unroll
                for (int r = 0; r < 4; ++r) {
                    float os = __shfl(scb[b], g * 4 + r, 64);
#pragma unroll
                    for (int d16 = 0; d16 < 4; ++d16) o[b][d16][r] *= os;
                }
        }
#pragma unroll
        for (int b = 0; b < 2; ++b) {
            float rsum = 0.f;
#pragma unroll
            for (int c = 0; c < 4; ++c) {
                float e0 = exp2f(s[c][b][0] - m_[b]);
                float e1 = exp2f(s[c][b][1] - m_[b]);
                float e2 = exp2f(s[c][b][2] - m_[b]);
                float e3 = exp2f(s[c][b][3] - m_[b]);
                rsum += (e0 + e1) + (e2 + e3);
                ushort4 pk = make_ushort4(f2bf(e0), f2bf(e1), f2bf(e2), f2bf(e3));
                *(ushort4*)&Ps[w][(b * 16 + li) * 64 + ((c * 16 + 4 * g) ^ (l7 << 3))] = pk;
            }
            rsum += __shfl_xor(rsum, 16, 64);
            rsum += __shfl_xor(rsum, 32, 64);
            l_[b] += rsum;
        }
        asm volatile("s_waitcnt lgkmcnt(0)" ::: "memory");
        __builtin_amdgcn_sched_barrier(0);

        __builtin_amdgcn_s_setprio(1);
#pragma unroll
        for (int ks = 0; ks < 2; ++ks) {
            int koff = (ks * 32 + g * 8) ^ (l7 << 3);
            s16x8 pf0 = *(const s16x8*)&Ps[w][li * 64 + koff];
            s16x8 pf1 = *(const s16x8*)&Ps[w][(16 + li) * 64 + koff];
#pragma unroll
            for (int d16 = 0; d16 < 4; ++d16) {
                s16x8 vf = *(const s16x8*)&Vs[cur][(d16 * 16 + li) * 64 + koff];
                o[0][d16] = __builtin_amdgcn_mfma_f32_16x16x32_bf16(pf0, vf, o[0][d16], 0, 0, 0);
                o[1][d16] = __builtin_amdgcn_mfma_f32_16x16x32_bf16(pf1, vf, o[1][d16], 0, 0, 0);
            }
        }
        __builtin_amdgcn_s_setprio(0);
        __syncthreads();
    }

#pragma unroll
    for (int b = 0; b < 2; ++b) {
        float il = 1.0f / l_[b];
#pragma unroll
        for (int r = 0; r < 4; ++r) {
            float iv = __shfl(il, g * 4 + r, 64);
            int qrow = q0 + w * 32 + b * 16 + g * 4 + r;
#pragma unroll
            for (int d16 = 0; d16 < 4; ++d16) {
                float v = o[b][d16][r] * iv;
                int col = (h << 6) + d16 * 16 + li;
                ctxb[(size_t)qrow * DMODEL + col] = f2bf(v);
            }
        }
    }
}

// ---------------------------------------------------------------------------
// LayerNorm over 768. BF=1 also emits bf16 copy.
// ---------------------------------------------------------------------------
template<int BF>
__global__ __launch_bounds__(256) void ln_kernel(const float* __restrict__ in,
    const float* __restrict__ gw, const float* __restrict__ bw,
    float* __restrict__ outf, u16* __restrict__ outb)
{
    __shared__ float red[8];
    const int row = blockIdx.x, tid = threadIdx.x;
    const float* x = in + (size_t)row * DMODEL;
    float v0 = x[tid], v1 = x[tid + 256], v2 = x[tid + 512];
    float s = v0 + v1 + v2;
#pragma unroll
    for (int off = 32; off > 0; off >>= 1) s += __shfl_xor(s, off, 64);
    const int wv = tid >> 6, lane = tid & 63;
    if (lane == 0) red[wv] = s;
    __syncthreads();
    float mu = (red[0] + red[1] + red[2] + red[3]) * (1.0f / DMODEL);
    float d0 = v0 - mu, d1 = v1 - mu, d2 = v2 - mu;
    float s2 = d0 * d0 + d1 * d1 + d2 * d2;
#pragma unroll
    for (int off = 32; off > 0; off >>= 1) s2 += __shfl_xor(s2, off, 64);
    if (lane == 0) red[4 + wv] = s2;
    __syncthreads();
    float var = (red[4] + red[5] + red[6] + red[7]) * (1.0f / DMODEL);
    float rstd = rsqrtf(var + 1e-5f);
    float y0 = d0 * rstd * gw[tid] + bw[tid];
    float y1 = d1 * rstd * gw[tid + 256] + bw[tid + 256];
    float y2 = d2 * rstd * gw[tid + 512] + bw[tid + 512];
    float* yo = outf + (size_t)row * DMODEL;
    yo[tid] = y0; yo[tid + 256] = y1; yo[tid + 512] = y2;
    if constexpr (BF) {
        u16* o = outb + (size_t)row * DMODEL;
        o[tid] = f2bf(y0); o[tid + 256] = f2bf(y1); o[tid + 512] = f2bf(y2);
    }
}

// ---------------------------------------------------------------------------
// Workspace (bytes):
//  xb@0 | Wqkvt@6291456 | Wot@9830400 | W1t@11010048 | W2t@15728640
//  bcat@20447232 | Qb@20456448 | Kb@26747904 | VTb@33039360 | ctxb@39330816
//  s1@45622272 | h@58205184 | hb@70788096 | ff1b@77079552 | t2@102245376
//  end 114.8 MB
// ---------------------------------------------------------------------------
extern "C" void kernel_launch(void* const* d_in, const int* in_sizes, int n_in,
                              void* d_out, int out_size, void* d_ws, size_t ws_size,
                              hipStream_t stream)
{
    const float* x  = (const float*)d_in[0];
    const float* Wq = (const float*)d_in[1];  const float* bq = (const float*)d_in[2];
    const float* Wk = (const float*)d_in[3];  const float* bk = (const float*)d_in[4];
    const float* Wv = (const float*)d_in[5];  const float* bv = (const float*)d_in[6];
    const float* Wo = (const float*)d_in[7];  const float* bo = (const float*)d_in[8];
    const float* W1 = (const float*)d_in[9];  const float* b1 = (const float*)d_in[10];
    const float* W2 = (const float*)d_in[11]; const float* b2 = (const float*)d_in[12];
    const float* g1 = (const float*)d_in[13]; const float* be1 = (const float*)d_in[14];
    const float* g2 = (const float*)d_in[15]; const float* be2 = (const float*)d_in[16];
    float* out = (float*)d_out;

    char* wsb = (char*)d_ws;
    u16*   xb    = (u16*)(wsb + 0);
    u16*   Wqkvt = (u16*)(wsb + 6291456);
    u16*   Wot   = (u16*)(wsb + 9830400);
    u16*   W1t   = (u16*)(wsb + 11010048);
    u16*   W2t   = (u16*)(wsb + 15728640);
    float* bcat  = (float*)(wsb + 20447232);
    u16*   Qb    = (u16*)(wsb + 20456448);
    u16*   Kb2   = (u16*)(wsb + 26747904);
    u16*   VTb   = (u16*)(wsb + 33039360);
    u16*   ctxb  = (u16*)(wsb + 39330816);
    float* s1    = (float*)(wsb + 45622272);
    float* h     = (float*)(wsb + 58205184);
    u16*   hb    = (u16*)(wsb + 70788096);
    u16*   ff1b  = (u16*)(wsb + 77079552);
    float* t2    = (float*)(wsb + 102245376);

    tobf16<<<1024, 256, 0, stream>>>(x, xb, 786432);
    wtrans<<<dim3(24, 24), 256, 0, stream>>>(Wq, Wqkvt, 768, 768, 0);
    wtrans<<<dim3(24, 24), 256, 0, stream>>>(Wk, Wqkvt, 768, 768, 768);
    wtrans<<<dim3(24, 24), 256, 0, stream>>>(Wv, Wqkvt, 768, 768, 1536);
    wtrans<<<dim3(24, 24), 256, 0, stream>>>(Wo, Wot, 768, 768, 0);
    wtrans<<<dim3(96, 24), 256, 0, stream>>>(W1, W1t, 768, 3072, 0);
    wtrans<<<dim3(24, 96), 256, 0, stream>>>(W2, W2t, 3072, 768, 0);
    bias_cat_kernel<<<9, 256, 0, stream>>>(bq, bk, bv, bcat);

    gemm_bf<128, 128, 0><<<dim3(18, 32), 256, 0, stream>>>(
        xb, Wqkvt, bcat, nullptr, nullptr, nullptr, Qb, Kb2, VTb, 2304, 768);
    attn128<<<dim3(32, 12), 256, 0, stream>>>(Qb, Kb2, VTb, ctxb);
    gemm_bf<64, 128, 1><<<dim3(6, 64), 256, 0, stream>>>(
        ctxb, Wot, bo, x, s1, nullptr, nullptr, nullptr, nullptr, 768, 768);
    ln_kernel<1><<<4096, 256, 0, stream>>>(s1, g1, be1, h, hb);
    gemm_bf<128, 128, 2><<<dim3(24, 32), 256, 0, stream>>>(
        hb, W1t, b1, nullptr, nullptr, ff1b, nullptr, nullptr, nullptr, 3072, 768);
    gemm_bf<64, 128, 1><<<dim3(6, 64), 256, 0, stream>>>(
        ff1b, W2t, b2, h, t2, nullptr, nullptr, nullptr, nullptr, 768, 3072);
    ln_kernel<0><<<4096, 256, 0, stream>>>(t2, g2, be2, out, nullptr);
}

// Round 5
// 386.147 us; speedup vs baseline: 1.9634x; 1.1540x over previous
//
#include <hip/hip_runtime.h>
#include <math.h>

#define TSEQ 4096
#define DMODEL 768
#define NHEADS 12
#define DKH 64
#define DFF 3072
#define LOG2E 1.44269504f

typedef __attribute__((ext_vector_type(4))) float f32x4;
typedef __attribute__((ext_vector_type(8))) short s16x8;
typedef unsigned short u16;
typedef unsigned int u32;

__device__ __forceinline__ u16 f2bf(float x) {
    u32 u = __builtin_bit_cast(u32, x);
    u32 r = u + 0x7FFFu + ((u >> 16) & 1u);
    return (u16)(r >> 16);
}
__device__ __forceinline__ float bf2f(u16 h) {
    u32 u = ((u32)h) << 16;
    return __builtin_bit_cast(float, u);
}

__device__ __forceinline__ void gll16(const void* g, void* lds) {
    __builtin_amdgcn_global_load_lds(
        (const __attribute__((address_space(1))) u32*)g,
        (__attribute__((address_space(3))) u32*)lds, 16, 0, 0);
}

// ---------------------------------------------------------------------------
// f32 -> bf16 cast, vectorized.
// ---------------------------------------------------------------------------
__global__ __launch_bounds__(256) void tobf16(const float* __restrict__ in,
                                              u16* __restrict__ out, int n4)
{
    int idx = blockIdx.x * 256 + threadIdx.x;
    for (int i = idx; i < n4; i += 262144) {
        float4 v = *(const float4*)(in + (size_t)i * 4);
        *(ushort4*)(out + (size_t)i * 4) =
            make_ushort4(f2bf(v.x), f2bf(v.y), f2bf(v.z), f2bf(v.w));
    }
}

// ---------------------------------------------------------------------------
// Transpose W [768][768] f32 -> bf16 B^T rows. z selects Wq/Wk/Wv/Wo.
// ---------------------------------------------------------------------------
__global__ __launch_bounds__(256) void wtrans4(
    const float* __restrict__ Wq, const float* __restrict__ Wk,
    const float* __restrict__ Wv, const float* __restrict__ Wo,
    u16* __restrict__ Wqkvt, u16* __restrict__ Wot)
{
    __shared__ float t[32 * 33];
    const int z = blockIdx.z;
    const float* W = (z == 0) ? Wq : (z == 1) ? Wk : (z == 2) ? Wv : Wo;
    u16* out = (z < 3) ? Wqkvt : Wot;
    const int nofs = (z < 3) ? z * 768 : 0;
    const int K = 768, N = 768;
    const int tid = threadIdx.x;
    const int kt = blockIdx.y << 5, nt = blockIdx.x << 5;
    const int r = tid >> 3, c4 = tid & 7;
    float4 v = *(const float4*)(W + (size_t)(kt + r) * N + nt + (c4 << 2));
    t[r * 33 + (c4 << 2) + 0] = v.x;
    t[r * 33 + (c4 << 2) + 1] = v.y;
    t[r * 33 + (c4 << 2) + 2] = v.z;
    t[r * 33 + (c4 << 2) + 3] = v.w;
    __syncthreads();
    float a0 = t[((c4 << 2) + 0) * 33 + r];
    float a1 = t[((c4 << 2) + 1) * 33 + r];
    float a2 = t[((c4 << 2) + 2) * 33 + r];
    float a3 = t[((c4 << 2) + 3) * 33 + r];
    u16* o = out + (size_t)(nofs + nt + r) * K + kt + (c4 << 2);
    *(ushort4*)o = make_ushort4(f2bf(a0), f2bf(a1), f2bf(a2), f2bf(a3));
}

__global__ __launch_bounds__(256) void wtrans(const float* __restrict__ W,
                                              u16* __restrict__ out,
                                              int K, int N)
{
    __shared__ float t[32 * 33];
    const int tid = threadIdx.x;
    const int kt = blockIdx.y << 5, nt = blockIdx.x << 5;
    const int r = tid >> 3, c4 = tid & 7;
    float4 v = *(const float4*)(W + (size_t)(kt + r) * N + nt + (c4 << 2));
    t[r * 33 + (c4 << 2) + 0] = v.x;
    t[r * 33 + (c4 << 2) + 1] = v.y;
    t[r * 33 + (c4 << 2) + 2] = v.z;
    t[r * 33 + (c4 << 2) + 3] = v.w;
    __syncthreads();
    float a0 = t[((c4 << 2) + 0) * 33 + r];
    float a1 = t[((c4 << 2) + 1) * 33 + r];
    float a2 = t[((c4 << 2) + 2) * 33 + r];
    float a3 = t[((c4 << 2) + 3) * 33 + r];
    u16* o = out + (size_t)(nt + r) * K + kt + (c4 << 2);
    *(ushort4*)o = make_ushort4(f2bf(a0), f2bf(a1), f2bf(a2), f2bf(a3));
}

__global__ __launch_bounds__(256) void bias_cat_kernel(const float* bq, const float* bk,
                                                       const float* bv, float* o)
{
    int i = blockIdx.x * 256 + threadIdx.x;
    if (i < 768) o[i] = bq[i];
    else if (i < 1536) o[i] = bk[i - 768];
    else if (i < 2304) o[i] = bv[i - 1536];
}

// ---------------------------------------------------------------------------
// bf16 MFMA GEMM. A[M][KP], B^T[N][KP] bf16. BK=64, 4 waves.
// LDS XOR-swizzle: slot s of row r holds global chunk s^(r&7) (2-way max).
// XCD-bijective block remap (nwg % 8 == 0 for all grids used).
// EPI 0: QKV (Q scaled by 0.125*log2e; Q/K head-major bf16; V^T bf16)
// EPI 1: f32 out = acc + bias + R
// EPI 2: relu(acc+bias) -> bf16 store, pitch N
// ---------------------------------------------------------------------------
template<int BM, int BN, int EPI>
__global__ __launch_bounds__(256) void gemm_bf(
    const u16* __restrict__ A, const u16* __restrict__ B,
    const float* __restrict__ bias, const float* __restrict__ R,
    float* __restrict__ Cf, u16* __restrict__ Cs,
    u16* __restrict__ Qb, u16* __restrict__ Kb, u16* __restrict__ VTb,
    int N, int KP)
{
    constexpr int FM = BM / 32, FN = BN / 32, NC = BN / 2, NCP = NC + 4;
    __shared__ u16 As[BM * 64];
    __shared__ u16 Bs[BN * 64];
    __shared__ float Ep[4 * 16 * NCP];

    const int tid = threadIdx.x;
    const int w = tid >> 6, lane = tid & 63;
    const int wr = w >> 1, wc = w & 1;
    const int li = lane & 15, g = lane >> 4;

    const int gX = gridDim.x;
    const int nwg = gridDim.x * gridDim.y;
    const int wid = blockIdx.y * gX + blockIdx.x;
    const int qc = nwg >> 3;
    const int nid = (wid & 7) * qc + (wid >> 3);
    const int m0 = (nid / gX) * BM, n0 = (nid % gX) * BN;

    f32x4 acc[FM][FN];
#pragma unroll
    for (int mi = 0; mi < FM; ++mi)
#pragma unroll
        for (int ni = 0; ni < FN; ++ni) acc[mi][ni] = (f32x4){0.f, 0.f, 0.f, 0.f};

    const int row8 = lane >> 3;
    const int cs = (lane & 7) ^ row8;     // pre-swizzled source chunk
    const int l7 = li & 7;

    for (int k0 = 0; k0 < KP; k0 += 64) {
        __syncthreads();
#pragma unroll
        for (int i = 0; i < BM / 32; ++i) {
            int inst = w * (BM / 32) + i;
            const u16* gp = A + (size_t)(m0 + inst * 8 + row8) * KP + k0 + cs * 8;
            gll16(gp, &As[inst * 512]);
        }
#pragma unroll
        for (int i = 0; i < BN / 32; ++i) {
            int inst = w * (BN / 32) + i;
            const u16* gp = B + (size_t)(n0 + inst * 8 + row8) * KP + k0 + cs * 8;
            gll16(gp, &Bs[inst * 512]);
        }
        __syncthreads();
        s16x8 af[FM][2], bfr[FN][2];
#pragma unroll
        for (int mi = 0; mi < FM; ++mi) {
            int Ra = wr * (BM / 2) + mi * 16 + li;
#pragma unroll
            for (int dc = 0; dc < 2; ++dc)
                af[mi][dc] = *(const s16x8*)&As[Ra * 64 + ((dc * 4 + g) ^ l7) * 8];
        }
#pragma unroll
        for (int ni = 0; ni < FN; ++ni) {
            int Rb = wc * (BN / 2) + ni * 16 + li;
#pragma unroll
            for (int dc = 0; dc < 2; ++dc)
                bfr[ni][dc] = *(const s16x8*)&Bs[Rb * 64 + ((dc * 4 + g) ^ l7) * 8];
        }
        __builtin_amdgcn_s_setprio(1);
#pragma unroll
        for (int mi = 0; mi < FM; ++mi)
#pragma unroll
            for (int ni = 0; ni < FN; ++ni) {
                acc[mi][ni] = __builtin_amdgcn_mfma_f32_16x16x32_bf16(
                    af[mi][0], bfr[ni][0], acc[mi][ni], 0, 0, 0);
                acc[mi][ni] = __builtin_amdgcn_mfma_f32_16x16x32_bf16(
                    af[mi][1], bfr[ni][1], acc[mi][ni], 0, 0, 0);
            }
        __builtin_amdgcn_s_setprio(0);
    }
    __syncthreads();

    float* ep = Ep + w * 16 * NCP;
    const int colbase = n0 + wc * NC;
    const int rr = lane >> 2, ch = lane & 3;

#pragma unroll
    for (int mi = 0; mi < FM; ++mi) {
#pragma unroll
        for (int ni = 0; ni < FN; ++ni)
#pragma unroll
            for (int r = 0; r < 4; ++r)
                ep[(g * 4 + r) * NCP + ni * 16 + li] = acc[mi][ni][r];
        asm volatile("s_waitcnt lgkmcnt(0)" ::: "memory");

        const int grow0 = m0 + wr * (BM / 2) + mi * 16;
        const int grow = grow0 + rr;

        if constexpr (EPI == 1) {
#pragma unroll
            for (int q = 0; q < NC / 16; ++q) {
                int col = ch * (NC / 4) + q * 4;
                f32x4 v = *(f32x4*)&ep[rr * NCP + col];
                int gn = colbase + col;
                float4 bb = *(const float4*)(bias + gn);
                float4 rv = *(const float4*)(R + (size_t)grow * N + gn);
                float4 ov;
                ov.x = v[0] + bb.x + rv.x; ov.y = v[1] + bb.y + rv.y;
                ov.z = v[2] + bb.z + rv.z; ov.w = v[3] + bb.w + rv.w;
                *(float4*)(Cf + (size_t)grow * N + gn) = ov;
            }
        } else if constexpr (EPI == 2) {
#pragma unroll
            for (int q = 0; q < NC / 16; ++q) {
                int col = ch * (NC / 4) + q * 4;
                f32x4 v = *(f32x4*)&ep[rr * NCP + col];
                int gn = colbase + col;
                float4 bb = *(const float4*)(bias + gn);
                float x0 = fmaxf(v[0] + bb.x, 0.f), x1 = fmaxf(v[1] + bb.y, 0.f);
                float x2 = fmaxf(v[2] + bb.z, 0.f), x3 = fmaxf(v[3] + bb.w, 0.f);
                *(ushort4*)(Cs + (size_t)grow * N + gn) =
                    make_ushort4(f2bf(x0), f2bf(x1), f2bf(x2), f2bf(x3));
            }
        } else {  // EPI 0: QKV
            const int seg = colbase / 768;
            const int hh = (colbase % 768) >> 6;
            if (seg < 2) {
                u16* dst = (seg == 0) ? Qb : Kb;
                const float sc2 = (seg == 0) ? 0.125f * LOG2E : 1.0f;
#pragma unroll
                for (int q = 0; q < NC / 16; ++q) {
                    int col = ch * (NC / 4) + q * 4;
                    f32x4 v = *(f32x4*)&ep[rr * NCP + col];
                    float4 bb = *(const float4*)(bias + colbase + col);
                    u16 h0 = f2bf((v[0] + bb.x) * sc2);
                    u16 h1 = f2bf((v[1] + bb.y) * sc2);
                    u16 h2 = f2bf((v[2] + bb.z) * sc2);
                    u16 h3 = f2bf((v[3] + bb.w) * sc2);
                    *(ushort4*)&dst[((size_t)(hh << 12) + grow) * 64 + col] =
                        make_ushort4(h0, h1, h2, h3);
                }
            } else {
                float bb = bias[colbase + lane];
                s16x8 pa, pb;
#pragma unroll
                for (int r2 = 0; r2 < 8; ++r2)
                    pa[r2] = (short)f2bf(ep[r2 * NCP + lane] + bb);
#pragma unroll
                for (int r2 = 0; r2 < 8; ++r2)
                    pb[r2] = (short)f2bf(ep[(8 + r2) * NCP + lane] + bb);
                u16* ov = VTb + ((size_t)(hh << 6) + lane) * TSEQ + grow0;
                *(s16x8*)(ov)     = pa;
                *(s16x8*)(ov + 8) = pb;
            }
        }
    }
}

// ---------------------------------------------------------------------------
// Flash attention, bf16 MFMA, causal. Uniform-work blocks: block = pair of
// 64-row q-tiles {p, 63-p} of one head -> exactly 65 k-tiles each. 4 waves,
// 16 q-rows/wave. Swapped QK^T, in-lane softmax, dbuf K/V via global_load_lds
// (pre-swizzled source, linear dest), defer-max (log2 domain, THR=8).
// ---------------------------------------------------------------------------
__global__ __launch_bounds__(256) void attn64(
    const u16* __restrict__ Qb, const u16* __restrict__ Kb,
    const u16* __restrict__ VTb, u16* __restrict__ ctxb)
{
    __shared__ u16 Ks[2][4096];   // [64 tok][64 d], row 128B, 8 swz slots
    __shared__ u16 Vs[2][4096];   // V^T [64 d][64 tok]
    __shared__ u16 Ps[4][1024];   // per-wave P [16 q][64 k]

    const int tid = threadIdx.x, w = tid >> 6, lane = tid & 63;
    const int g = lane >> 4, li = lane & 15, l7 = lane & 7;
    const int p = blockIdx.x;                 // pair index 0..31
    const int h = blockIdx.y;

    const u16* Qh = Qb + ((size_t)h << 18);
    const u16* Kh = Kb + ((size_t)h << 18);
    const u16* Vh = VTb + ((size_t)h << 18);

    const int row8 = lane >> 3;
    const int cs = (lane & 7) ^ row8;         // pre-swizzled source chunk

    for (int pass = 0; pass < 2; ++pass) {
        const int qbk = pass ? 63 - p : p;
        const int q0 = qbk << 6;
        const int nkb = qbk + 1;

        s16x8 qf[2];
#pragma unroll
        for (int dc = 0; dc < 2; ++dc)
            qf[dc] = *(const s16x8*)(Qh + (size_t)(q0 + w * 16 + li) * 64 + dc * 32 + g * 8);

        f32x4 o[4];
        float m_ = -1e30f, l_ = 0.f;
#pragma unroll
        for (int d16 = 0; d16 < 4; ++d16) o[d16] = (f32x4){0.f, 0.f, 0.f, 0.f};

        // prologue: stage tile 0 into buffer 0
#pragma unroll
        for (int i = 0; i < 2; ++i) {
            int inst = w * 2 + i;
            int row = inst * 8 + row8;
            gll16(Kh + (size_t)row * 64 + cs * 8, &Ks[0][inst * 512]);
            gll16(Vh + (size_t)row * TSEQ + cs * 8, &Vs[0][inst * 512]);
        }
        __syncthreads();

        for (int kb = 0; kb < nkb; ++kb) {
            const int cur = kb & 1;
            if (kb + 1 < nkb) {
                const int kn = kb + 1;
#pragma unroll
                for (int i = 0; i < 2; ++i) {
                    int inst = w * 2 + i;
                    int row = inst * 8 + row8;
                    gll16(Kh + (size_t)((kn << 6) + row) * 64 + cs * 8, &Ks[cur ^ 1][inst * 512]);
                    gll16(Vh + (size_t)row * TSEQ + (kn << 6) + cs * 8, &Vs[cur ^ 1][inst * 512]);
                }
            }

            // QK^T swapped: s[c] rows k = c*16+g*4+r, col q = li
            f32x4 s[4];
            __builtin_amdgcn_s_setprio(1);
#pragma unroll
            for (int c = 0; c < 4; ++c) {
                s[c] = (f32x4){0.f, 0.f, 0.f, 0.f};
                s16x8 a0 = *(const s16x8*)&Ks[cur][(c * 16 + li) * 64 + ((g) ^ l7) * 8];
                s16x8 a1 = *(const s16x8*)&Ks[cur][(c * 16 + li) * 64 + ((4 + g) ^ l7) * 8];
                s[c] = __builtin_amdgcn_mfma_f32_16x16x32_bf16(a0, qf[0], s[c], 0, 0, 0);
                s[c] = __builtin_amdgcn_mfma_f32_16x16x32_bf16(a1, qf[1], s[c], 0, 0, 0);
            }
            __builtin_amdgcn_s_setprio(0);

            if (kb == qbk) {   // only the diagonal tile needs masking
#pragma unroll
                for (int c = 0; c < 4; ++c)
#pragma unroll
                    for (int r = 0; r < 4; ++r) {
                        int kglob = (kb << 6) + c * 16 + g * 4 + r;
                        int qglob = q0 + w * 16 + li;
                        if (kglob > qglob) s[c][r] = -1e30f;
                    }
            }

            // in-lane row max (row q = li), cross-g combine
            float v0 = fmaxf(fmaxf(s[0][0], s[0][1]), fmaxf(s[0][2], s[0][3]));
            float v1 = fmaxf(fmaxf(s[1][0], s[1][1]), fmaxf(s[1][2], s[1][3]));
            float v2 = fmaxf(fmaxf(s[2][0], s[2][1]), fmaxf(s[2][2], s[2][3]));
            float v3 = fmaxf(fmaxf(s[3][0], s[3][1]), fmaxf(s[3][2], s[3][3]));
            float pm = fmaxf(fmaxf(v0, v1), fmaxf(v2, v3));
            pm = fmaxf(pm, __shfl_xor(pm, 16, 64));
            pm = fmaxf(pm, __shfl_xor(pm, 32, 64));

            int ok = (pm <= m_ + 8.f);
            if (!__all(ok)) {
                float mn = fmaxf(m_, pm);
                float sc2 = exp2f(m_ - mn);
                m_ = mn;
                l_ *= sc2;
#pragma unroll
                for (int r = 0; r < 4; ++r) {
                    float os = __shfl(sc2, g * 4 + r, 64);
#pragma unroll
                    for (int d16 = 0; d16 < 4; ++d16) o[d16][r] *= os;
                }
            }

            float rsum = 0.f;
#pragma unroll
            for (int c = 0; c < 4; ++c) {
                float e0 = exp2f(s[c][0] - m_);
                float e1 = exp2f(s[c][1] - m_);
                float e2 = exp2f(s[c][2] - m_);
                float e3 = exp2f(s[c][3] - m_);
                rsum += (e0 + e1) + (e2 + e3);
                *(ushort4*)&Ps[w][li * 64 + ((c * 16 + 4 * g) ^ (l7 << 3))] =
                    make_ushort4(f2bf(e0), f2bf(e1), f2bf(e2), f2bf(e3));
            }
            rsum += __shfl_xor(rsum, 16, 64);
            rsum += __shfl_xor(rsum, 32, 64);
            l_ += rsum;

            asm volatile("s_waitcnt lgkmcnt(0)" ::: "memory");
            __builtin_amdgcn_sched_barrier(0);

            __builtin_amdgcn_s_setprio(1);
#pragma unroll
            for (int ks = 0; ks < 2; ++ks) {
                int koff = ((ks * 4 + g) ^ l7) * 8;
                s16x8 pf = *(const s16x8*)&Ps[w][li * 64 + ((ks * 32 + g * 8) ^ (l7 << 3))];
#pragma unroll
                for (int d16 = 0; d16 < 4; ++d16) {
                    s16x8 vf = *(const s16x8*)&Vs[cur][(d16 * 16 + li) * 64 + koff];
                    o[d16] = __builtin_amdgcn_mfma_f32_16x16x32_bf16(pf, vf, o[d16], 0, 0, 0);
                }
            }
            __builtin_amdgcn_s_setprio(0);
            __syncthreads();
        }

        // write ctx bf16 [T][768]
        float il = 1.0f / l_;
#pragma unroll
        for (int r = 0; r < 4; ++r) {
            float iv = __shfl(il, g * 4 + r, 64);
            int qrow = q0 + w * 16 + g * 4 + r;
#pragma unroll
            for (int d16 = 0; d16 < 4; ++d16) {
                int col = (h << 6) + d16 * 16 + li;
                ctxb[(size_t)qrow * DMODEL + col] = f2bf(o[d16][r] * iv);
            }
        }
        __syncthreads();   // pass 0's buffers free before pass 1 staging
    }
}

// ---------------------------------------------------------------------------
// LayerNorm over 768. BF=1 also emits bf16 copy.
// ---------------------------------------------------------------------------
template<int BF>
__global__ __launch_bounds__(256) void ln_kernel(const float* __restrict__ in,
    const float* __restrict__ gw, const float* __restrict__ bw,
    float* __restrict__ outf, u16* __restrict__ outb)
{
    __shared__ float red[8];
    const int row = blockIdx.x, tid = threadIdx.x;
    const float* x = in + (size_t)row * DMODEL;
    float v0 = x[tid], v1 = x[tid + 256], v2 = x[tid + 512];
    float s = v0 + v1 + v2;
#pragma unroll
    for (int off = 32; off > 0; off >>= 1) s += __shfl_xor(s, off, 64);
    const int wv = tid >> 6, lane = tid & 63;
    if (lane == 0) red[wv] = s;
    __syncthreads();
    float mu = (red[0] + red[1] + red[2] + red[3]) * (1.0f / DMODEL);
    float d0 = v0 - mu, d1 = v1 - mu, d2 = v2 - mu;
    float s2 = d0 * d0 + d1 * d1 + d2 * d2;
#pragma unroll
    for (int off = 32; off > 0; off >>= 1) s2 += __shfl_xor(s2, off, 64);
    if (lane == 0) red[4 + wv] = s2;
    __syncthreads();
    float var = (red[4] + red[5] + red[6] + red[7]) * (1.0f / DMODEL);
    float rstd = rsqrtf(var + 1e-5f);
    float y0 = d0 * rstd * gw[tid] + bw[tid];
    float y1 = d1 * rstd * gw[tid + 256] + bw[tid + 256];
    float y2 = d2 * rstd * gw[tid + 512] + bw[tid + 512];
    float* yo = outf + (size_t)row * DMODEL;
    yo[tid] = y0; yo[tid + 256] = y1; yo[tid + 512] = y2;
    if constexpr (BF) {
        u16* o = outb + (size_t)row * DMODEL;
        o[tid] = f2bf(y0); o[tid + 256] = f2bf(y1); o[tid + 512] = f2bf(y2);
    }
}

// ---------------------------------------------------------------------------
extern "C" void kernel_launch(void* const* d_in, const int* in_sizes, int n_in,
                              void* d_out, int out_size, void* d_ws, size_t ws_size,
                              hipStream_t stream)
{
    const float* x  = (const float*)d_in[0];
    const float* Wq = (const float*)d_in[1];  const float* bq = (const float*)d_in[2];
    const float* Wk = (const float*)d_in[3];  const float* bk = (const float*)d_in[4];
    const float* Wv = (const float*)d_in[5];  const float* bv = (const float*)d_in[6];
    const float* Wo = (const float*)d_in[7];  const float* bo = (const float*)d_in[8];
    const float* W1 = (const float*)d_in[9];  const float* b1 = (const float*)d_in[10];
    const float* W2 = (const float*)d_in[11]; const float* b2 = (const float*)d_in[12];
    const float* g1 = (const float*)d_in[13]; const float* be1 = (const float*)d_in[14];
    const float* g2 = (const float*)d_in[15]; const float* be2 = (const float*)d_in[16];
    float* out = (float*)d_out;

    char* wsb = (char*)d_ws;
    u16*   xb    = (u16*)(wsb + 0);
    u16*   Wqkvt = (u16*)(wsb + 6291456);
    u16*   Wot   = (u16*)(wsb + 9830400);
    u16*   W1t   = (u16*)(wsb + 11010048);
    u16*   W2t   = (u16*)(wsb + 15728640);
    float* bcat  = (float*)(wsb + 20447232);
    u16*   Qb    = (u16*)(wsb + 20456448);
    u16*   Kb2   = (u16*)(wsb + 26747904);
    u16*   VTb   = (u16*)(wsb + 33039360);
    u16*   ctxb  = (u16*)(wsb + 39330816);
    float* s1    = (float*)(wsb + 45622272);
    float* h     = (float*)(wsb + 58205184);
    u16*   hb    = (u16*)(wsb + 70788096);
    u16*   ff1b  = (u16*)(wsb + 77079552);
    float* t2    = (float*)(wsb + 102245376);

    tobf16<<<1024, 256, 0, stream>>>(x, xb, 786432);
    wtrans4<<<dim3(24, 24, 4), 256, 0, stream>>>(Wq, Wk, Wv, Wo, Wqkvt, Wot);
    wtrans<<<dim3(96, 24), 256, 0, stream>>>(W1, W1t, 768, 3072);
    wtrans<<<dim3(24, 96), 256, 0, stream>>>(W2, W2t, 3072, 768);
    bias_cat_kernel<<<9, 256, 0, stream>>>(bq, bk, bv, bcat);

    gemm_bf<128, 128, 0><<<dim3(18, 32), 256, 0, stream>>>(
        xb, Wqkvt, bcat, nullptr, nullptr, nullptr, Qb, Kb2, VTb, 2304, 768);
    attn64<<<dim3(32, 12), 256, 0, stream>>>(Qb, Kb2, VTb, ctxb);
    gemm_bf<64, 128, 1><<<dim3(6, 64), 256, 0, stream>>>(
        ctxb, Wot, bo, x, s1, nullptr, nullptr, nullptr, nullptr, 768, 768);
    ln_kernel<1><<<4096, 256, 0, stream>>>(s1, g1, be1, h, hb);
    gemm_bf<128, 128, 2><<<dim3(24, 32), 256, 0, stream>>>(
        hb, W1t, b1, nullptr, nullptr, ff1b, nullptr, nullptr, nullptr, 3072, 768);
    gemm_bf<64, 128, 1><<<dim3(6, 64), 256, 0, stream>>>(
        ff1b, W2t, b2, h, t2, nullptr, nullptr, nullptr, nullptr, 768, 3072);
    ln_kernel<0><<<4096, 256, 0, stream>>>(t2, g2, be2, out, nullptr);
}

// Round 7
// 372.722 us; speedup vs baseline: 2.0341x; 1.0360x over previous
//
#include <hip/hip_runtime.h>
#include <math.h>

#define TSEQ 4096
#define DMODEL 768
#define NHEADS 12
#define DKH 64
#define DFF 3072
#define LOG2E 1.44269504f

typedef __attribute__((ext_vector_type(4))) float f32x4;
typedef __attribute__((ext_vector_type(8))) short s16x8;
typedef unsigned short u16;
typedef unsigned int u32;

__device__ __forceinline__ u16 f2bf(float x) {
    u32 u = __builtin_bit_cast(u32, x);
    u32 r = u + 0x7FFFu + ((u >> 16) & 1u);
    return (u16)(r >> 16);
}
__device__ __forceinline__ float bf2f(u16 h) {
    u32 u = ((u32)h) << 16;
    return __builtin_bit_cast(float, u);
}
__device__ __forceinline__ u32 cvtpk(float lo, float hi) {
    u32 r;
    asm("v_cvt_pk_bf16_f32 %0, %1, %2" : "=v"(r) : "v"(lo), "v"(hi));
    return r;
}

__device__ __forceinline__ void gll16(const void* g, void* lds) {
    __builtin_amdgcn_global_load_lds(
        (const __attribute__((address_space(1))) u32*)g,
        (__attribute__((address_space(3))) u32*)lds, 16, 0, 0);
}

// ---------------------------------------------------------------------------
// f32 -> bf16 cast, vectorized.
// ---------------------------------------------------------------------------
__global__ __launch_bounds__(256) void tobf16(const float* __restrict__ in,
                                              u16* __restrict__ out, int n4)
{
    int idx = blockIdx.x * 256 + threadIdx.x;
    for (int i = idx; i < n4; i += 262144) {
        float4 v = *(const float4*)(in + (size_t)i * 4);
        *(ushort4*)(out + (size_t)i * 4) =
            make_ushort4(f2bf(v.x), f2bf(v.y), f2bf(v.z), f2bf(v.w));
    }
}

// ---------------------------------------------------------------------------
// Transpose W [768][768] f32 -> bf16 B^T rows. z selects Wq/Wk/Wv/Wo.
// ---------------------------------------------------------------------------
__global__ __launch_bounds__(256) void wtrans4(
    const float* __restrict__ Wq, const float* __restrict__ Wk,
    const float* __restrict__ Wv, const float* __restrict__ Wo,
    u16* __restrict__ Wqkvt, u16* __restrict__ Wot)
{
    __shared__ float t[32 * 33];
    const int z = blockIdx.z;
    const float* W = (z == 0) ? Wq : (z == 1) ? Wk : (z == 2) ? Wv : Wo;
    u16* out = (z < 3) ? Wqkvt : Wot;
    const int nofs = (z < 3) ? z * 768 : 0;
    const int K = 768, N = 768;
    const int tid = threadIdx.x;
    const int kt = blockIdx.y << 5, nt = blockIdx.x << 5;
    const int r = tid >> 3, c4 = tid & 7;
    float4 v = *(const float4*)(W + (size_t)(kt + r) * N + nt + (c4 << 2));
    t[r * 33 + (c4 << 2) + 0] = v.x;
    t[r * 33 + (c4 << 2) + 1] = v.y;
    t[r * 33 + (c4 << 2) + 2] = v.z;
    t[r * 33 + (c4 << 2) + 3] = v.w;
    __syncthreads();
    float a0 = t[((c4 << 2) + 0) * 33 + r];
    float a1 = t[((c4 << 2) + 1) * 33 + r];
    float a2 = t[((c4 << 2) + 2) * 33 + r];
    float a3 = t[((c4 << 2) + 3) * 33 + r];
    u16* o = out + (size_t)(nofs + nt + r) * K + kt + (c4 << 2);
    *(ushort4*)o = make_ushort4(f2bf(a0), f2bf(a1), f2bf(a2), f2bf(a3));
}

__global__ __launch_bounds__(256) void wtrans(const float* __restrict__ W,
                                              u16* __restrict__ out,
                                              int K, int N)
{
    __shared__ float t[32 * 33];
    const int tid = threadIdx.x;
    const int kt = blockIdx.y << 5, nt = blockIdx.x << 5;
    const int r = tid >> 3, c4 = tid & 7;
    float4 v = *(const float4*)(W + (size_t)(kt + r) * N + nt + (c4 << 2));
    t[r * 33 + (c4 << 2) + 0] = v.x;
    t[r * 33 + (c4 << 2) + 1] = v.y;
    t[r * 33 + (c4 << 2) + 2] = v.z;
    t[r * 33 + (c4 << 2) + 3] = v.w;
    __syncthreads();
    float a0 = t[((c4 << 2) + 0) * 33 + r];
    float a1 = t[((c4 << 2) + 1) * 33 + r];
    float a2 = t[((c4 << 2) + 2) * 33 + r];
    float a3 = t[((c4 << 2) + 3) * 33 + r];
    u16* o = out + (size_t)(nt + r) * K + kt + (c4 << 2);
    *(ushort4*)o = make_ushort4(f2bf(a0), f2bf(a1), f2bf(a2), f2bf(a3));
}

__global__ __launch_bounds__(256) void bias_cat_kernel(const float* bq, const float* bk,
                                                       const float* bv, float* o)
{
    int i = blockIdx.x * 256 + threadIdx.x;
    if (i < 768) o[i] = bq[i];
    else if (i < 1536) o[i] = bk[i - 768];
    else if (i < 2304) o[i] = bv[i - 1536];
}

// ---------------------------------------------------------------------------
// bf16 MFMA GEMM. A[M][KP], B^T[N][KP] bf16. BK=64, 4 waves.
// LDS XOR-swizzle (pre-swizzled global source, swizzled read). XCD remap.
// EPI 0: QKV (Q scaled by 0.125*log2e; Q/K head-major bf16; V^T bf16)
// EPI 1: f32 out = acc + bias + R
// EPI 2: relu(acc+bias) -> bf16 store, pitch N
// ---------------------------------------------------------------------------
template<int BM, int BN, int EPI>
__global__ __launch_bounds__(256) void gemm_bf(
    const u16* __restrict__ A, const u16* __restrict__ B,
    const float* __restrict__ bias, const float* __restrict__ R,
    float* __restrict__ Cf, u16* __restrict__ Cs,
    u16* __restrict__ Qb, u16* __restrict__ Kb, u16* __restrict__ VTb,
    int N, int KP)
{
    constexpr int FM = BM / 32, FN = BN / 32, NC = BN / 2, NCP = NC + 4;
    __shared__ u16 As[BM * 64];
    __shared__ u16 Bs[BN * 64];
    __shared__ float Ep[4 * 16 * NCP];

    const int tid = threadIdx.x;
    const int w = tid >> 6, lane = tid & 63;
    const int wr = w >> 1, wc = w & 1;
    const int li = lane & 15, g = lane >> 4;

    const int gX = gridDim.x;
    const int nwg = gridDim.x * gridDim.y;
    const int wid = blockIdx.y * gX + blockIdx.x;
    const int qc = nwg >> 3;
    const int nid = (wid & 7) * qc + (wid >> 3);
    const int m0 = (nid / gX) * BM, n0 = (nid % gX) * BN;

    f32x4 acc[FM][FN];
#pragma unroll
    for (int mi = 0; mi < FM; ++mi)
#pragma unroll
        for (int ni = 0; ni < FN; ++ni) acc[mi][ni] = (f32x4){0.f, 0.f, 0.f, 0.f};

    const int row8 = lane >> 3;
    const int cs = (lane & 7) ^ row8;
    const int l7 = li & 7;

    for (int k0 = 0; k0 < KP; k0 += 64) {
        __syncthreads();
#pragma unroll
        for (int i = 0; i < BM / 32; ++i) {
            int inst = w * (BM / 32) + i;
            const u16* gp = A + (size_t)(m0 + inst * 8 + row8) * KP + k0 + cs * 8;
            gll16(gp, &As[inst * 512]);
        }
#pragma unroll
        for (int i = 0; i < BN / 32; ++i) {
            int inst = w * (BN / 32) + i;
            const u16* gp = B + (size_t)(n0 + inst * 8 + row8) * KP + k0 + cs * 8;
            gll16(gp, &Bs[inst * 512]);
        }
        __syncthreads();
        s16x8 af[FM][2], bfr[FN][2];
#pragma unroll
        for (int mi = 0; mi < FM; ++mi) {
            int Ra = wr * (BM / 2) + mi * 16 + li;
#pragma unroll
            for (int dc = 0; dc < 2; ++dc)
                af[mi][dc] = *(const s16x8*)&As[Ra * 64 + ((dc * 4 + g) ^ l7) * 8];
        }
#pragma unroll
        for (int ni = 0; ni < FN; ++ni) {
            int Rb = wc * (BN / 2) + ni * 16 + li;
#pragma unroll
            for (int dc = 0; dc < 2; ++dc)
                bfr[ni][dc] = *(const s16x8*)&Bs[Rb * 64 + ((dc * 4 + g) ^ l7) * 8];
        }
        __builtin_amdgcn_s_setprio(1);
#pragma unroll
        for (int mi = 0; mi < FM; ++mi)
#pragma unroll
            for (int ni = 0; ni < FN; ++ni) {
                acc[mi][ni] = __builtin_amdgcn_mfma_f32_16x16x32_bf16(
                    af[mi][0], bfr[ni][0], acc[mi][ni], 0, 0, 0);
                acc[mi][ni] = __builtin_amdgcn_mfma_f32_16x16x32_bf16(
                    af[mi][1], bfr[ni][1], acc[mi][ni], 0, 0, 0);
            }
        __builtin_amdgcn_s_setprio(0);
    }
    __syncthreads();

    float* ep = Ep + w * 16 * NCP;
    const int colbase = n0 + wc * NC;
    const int rr = lane >> 2, ch = lane & 3;

#pragma unroll
    for (int mi = 0; mi < FM; ++mi) {
#pragma unroll
        for (int ni = 0; ni < FN; ++ni)
#pragma unroll
            for (int r = 0; r < 4; ++r)
                ep[(g * 4 + r) * NCP + ni * 16 + li] = acc[mi][ni][r];
        asm volatile("s_waitcnt lgkmcnt(0)" ::: "memory");

        const int grow0 = m0 + wr * (BM / 2) + mi * 16;
        const int grow = grow0 + rr;

        if constexpr (EPI == 1) {
#pragma unroll
            for (int q = 0; q < NC / 16; ++q) {
                int col = ch * (NC / 4) + q * 4;
                f32x4 v = *(f32x4*)&ep[rr * NCP + col];
                int gn = colbase + col;
                float4 bb = *(const float4*)(bias + gn);
                float4 rv = *(const float4*)(R + (size_t)grow * N + gn);
                float4 ov;
                ov.x = v[0] + bb.x + rv.x; ov.y = v[1] + bb.y + rv.y;
                ov.z = v[2] + bb.z + rv.z; ov.w = v[3] + bb.w + rv.w;
                *(float4*)(Cf + (size_t)grow * N + gn) = ov;
            }
        } else if constexpr (EPI == 2) {
#pragma unroll
            for (int q = 0; q < NC / 16; ++q) {
                int col = ch * (NC / 4) + q * 4;
                f32x4 v = *(f32x4*)&ep[rr * NCP + col];
                int gn = colbase + col;
                float4 bb = *(const float4*)(bias + gn);
                float x0 = fmaxf(v[0] + bb.x, 0.f), x1 = fmaxf(v[1] + bb.y, 0.f);
                float x2 = fmaxf(v[2] + bb.z, 0.f), x3 = fmaxf(v[3] + bb.w, 0.f);
                *(ushort4*)(Cs + (size_t)grow * N + gn) =
                    make_ushort4(f2bf(x0), f2bf(x1), f2bf(x2), f2bf(x3));
            }
        } else {  // EPI 0: QKV
            const int seg = colbase / 768;
            const int hh = (colbase % 768) >> 6;
            if (seg < 2) {
                u16* dst = (seg == 0) ? Qb : Kb;
                const float sc2 = (seg == 0) ? 0.125f * LOG2E : 1.0f;
#pragma unroll
                for (int q = 0; q < NC / 16; ++q) {
                    int col = ch * (NC / 4) + q * 4;
                    f32x4 v = *(f32x4*)&ep[rr * NCP + col];
                    float4 bb = *(const float4*)(bias + colbase + col);
                    u16 h0 = f2bf((v[0] + bb.x) * sc2);
                    u16 h1 = f2bf((v[1] + bb.y) * sc2);
                    u16 h2 = f2bf((v[2] + bb.z) * sc2);
                    u16 h3 = f2bf((v[3] + bb.w) * sc2);
                    *(ushort4*)&dst[((size_t)(hh << 12) + grow) * 64 + col] =
                        make_ushort4(h0, h1, h2, h3);
                }
            } else {
                float bb = bias[colbase + lane];
                s16x8 pa, pb;
#pragma unroll
                for (int r2 = 0; r2 < 8; ++r2)
                    pa[r2] = (short)f2bf(ep[r2 * NCP + lane] + bb);
#pragma unroll
                for (int r2 = 0; r2 < 8; ++r2)
                    pb[r2] = (short)f2bf(ep[(8 + r2) * NCP + lane] + bb);
                u16* ov = VTb + ((size_t)(hh << 6) + lane) * TSEQ + grow0;
                *(s16x8*)(ov)     = pa;
                *(s16x8*)(ov + 8) = pb;
            }
        }
    }
}

// ---------------------------------------------------------------------------
// Flash attention, bf16 MFMA, causal. Uniform-work blocks (pair {p, 63-p}),
// 1D grid with head-grouped XCD mapping: nid=(wid&7)*48+(wid>>3),
// head=nid/32 -> each XCD serves 1.5 heads, K/V L2-resident.
// Swapped QK^T, in-lane softmax with per-lane-partial defer-max (cross-lane
// only on rescale path / epilogue), cvt_pk P->bf16, dbuf K/V via
// global_load_lds (pre-swizzled source).
// ---------------------------------------------------------------------------
__global__ __launch_bounds__(256) void attn64(
    const u16* __restrict__ Qb, const u16* __restrict__ Kb,
    const u16* __restrict__ VTb, u16* __restrict__ ctxb)
{
    __shared__ u16 Ks[2][4096];   // [64 tok][64 d], 8 swizzle slots/row
    __shared__ u16 Vs[2][4096];   // V^T [64 d][64 tok]
    __shared__ u16 Ps[4][1024];   // per-wave P [16 q][64 k]

    const int tid = threadIdx.x, w = tid >> 6, lane = tid & 63;
    const int g = lane >> 4, li = lane & 15, l7 = lane & 7;
    const int wid = blockIdx.x;
    const int nid = (wid & 7) * 48 + (wid >> 3);   // head-grouped XCD mapping
    const int h = nid >> 5;
    const int p = nid & 31;

    const u16* Qh = Qb + ((size_t)h << 18);
    const u16* Kh = Kb + ((size_t)h << 18);
    const u16* Vh = VTb + ((size_t)h << 18);

    const int row8 = lane >> 3;
    const int cs = (lane & 7) ^ row8;

    for (int pass = 0; pass < 2; ++pass) {
        const int qbk = pass ? 63 - p : p;
        const int q0 = qbk << 6;
        const int nkb = qbk + 1;

        s16x8 qf[2];
#pragma unroll
        for (int dc = 0; dc < 2; ++dc)
            qf[dc] = *(const s16x8*)(Qh + (size_t)(q0 + w * 16 + li) * 64 + dc * 32 + g * 8);

        // per-lane staging base pointers (advance by constants per k-tile)
        const u16* kbase = Kh + (size_t)(w * 16 + row8) * 64 + cs * 8;        // +4096/tile
        const u16* vbase = Vh + (size_t)(w * 16 + row8) * TSEQ + cs * 8;      // +64/tile

        f32x4 o[4];
        float m_ = -1e30f, l_ = 0.f;
#pragma unroll
        for (int d16 = 0; d16 < 4; ++d16) o[d16] = (f32x4){0.f, 0.f, 0.f, 0.f};

        // prologue: stage tile 0 into buffer 0
#pragma unroll
        for (int i = 0; i < 2; ++i) {
            int inst = w * 2 + i;
            gll16(kbase + (size_t)i * 512, &Ks[0][inst * 512]);
            gll16(vbase + (size_t)i * 8 * TSEQ, &Vs[0][inst * 512]);
        }
        __syncthreads();

        for (int kb = 0; kb < nkb; ++kb) {
            const int cur = kb & 1;
            if (kb + 1 < nkb) {
                const int kn = kb + 1;
#pragma unroll
                for (int i = 0; i < 2; ++i) {
                    int inst = w * 2 + i;
                    gll16(kbase + (size_t)kn * 4096 + (size_t)i * 512, &Ks[cur ^ 1][inst * 512]);
                    gll16(vbase + (size_t)kn * 64 + (size_t)i * 8 * TSEQ, &Vs[cur ^ 1][inst * 512]);
                }
            }

            // QK^T swapped: s[c] rows k = c*16+g*4+r, col q = li
            f32x4 s[4];
            __builtin_amdgcn_s_setprio(1);
#pragma unroll
            for (int c = 0; c < 4; ++c) {
                s[c] = (f32x4){0.f, 0.f, 0.f, 0.f};
                s16x8 a0 = *(const s16x8*)&Ks[cur][(c * 16 + li) * 64 + ((g) ^ l7) * 8];
                s16x8 a1 = *(const s16x8*)&Ks[cur][(c * 16 + li) * 64 + ((4 + g) ^ l7) * 8];
                s[c] = __builtin_amdgcn_mfma_f32_16x16x32_bf16(a0, qf[0], s[c], 0, 0, 0);
                s[c] = __builtin_amdgcn_mfma_f32_16x16x32_bf16(a1, qf[1], s[c], 0, 0, 0);
            }
            __builtin_amdgcn_s_setprio(0);

            if (kb == qbk) {   // diagonal tile mask
#pragma unroll
                for (int c = 0; c < 4; ++c)
#pragma unroll
                    for (int r = 0; r < 4; ++r) {
                        int kglob = (kb << 6) + c * 16 + g * 4 + r;
                        int qglob = q0 + w * 16 + li;
                        if (kglob > qglob) s[c][r] = -1e30f;
                    }
            }

            // per-lane PARTIAL max (no cross-lane in steady state)
            float v0 = fmaxf(fmaxf(s[0][0], s[0][1]), fmaxf(s[0][2], s[0][3]));
            float v1 = fmaxf(fmaxf(s[1][0], s[1][1]), fmaxf(s[1][2], s[1][3]));
            float v2 = fmaxf(fmaxf(s[2][0], s[2][1]), fmaxf(s[2][2], s[2][3]));
            float v3 = fmaxf(fmaxf(s[3][0], s[3][1]), fmaxf(s[3][2], s[3][3]));
            float pmp = fmaxf(fmaxf(v0, v1), fmaxf(v2, v3));

            if (!__all(pmp <= m_ + 8.f)) {
                // rare path: full row max + rescale
                float pm = fmaxf(pmp, __shfl_xor(pmp, 16, 64));
                pm = fmaxf(pm, __shfl_xor(pm, 32, 64));
                float mn = fmaxf(m_, pm);
                float sc2 = exp2f(m_ - mn);
                m_ = mn;
                l_ *= sc2;
#pragma unroll
                for (int r = 0; r < 4; ++r) {
                    float os = __shfl(sc2, g * 4 + r, 64);
#pragma unroll
                    for (int d16 = 0; d16 < 4; ++d16) o[d16][r] *= os;
                }
            }

#pragma unroll
            for (int c = 0; c < 4; ++c) {
                float e0 = exp2f(s[c][0] - m_);
                float e1 = exp2f(s[c][1] - m_);
                float e2 = exp2f(s[c][2] - m_);
                float e3 = exp2f(s[c][3] - m_);
                l_ += (e0 + e1) + (e2 + e3);      // per-lane partial sum
                u32 r0 = cvtpk(e0, e1);
                u32 r1 = cvtpk(e2, e3);
                *(uint2*)&Ps[w][li * 64 + ((c * 16 + 4 * g) ^ (l7 << 3))] =
                    make_uint2(r0, r1);
            }

            asm volatile("s_waitcnt lgkmcnt(0)" ::: "memory");
            __builtin_amdgcn_sched_barrier(0);

            __builtin_amdgcn_s_setprio(1);
#pragma unroll
            for (int ks = 0; ks < 2; ++ks) {
                int koff = ((ks * 4 + g) ^ l7) * 8;
                s16x8 pf = *(const s16x8*)&Ps[w][li * 64 + ((ks * 32 + g * 8) ^ (l7 << 3))];
#pragma unroll
                for (int d16 = 0; d16 < 4; ++d16) {
                    s16x8 vf = *(const s16x8*)&Vs[cur][(d16 * 16 + li) * 64 + koff];
                    o[d16] = __builtin_amdgcn_mfma_f32_16x16x32_bf16(pf, vf, o[d16], 0, 0, 0);
                }
            }
            __builtin_amdgcn_s_setprio(0);
            __syncthreads();
        }

        // epilogue: combine per-lane l_ partials across g, normalize, write
        l_ += __shfl_xor(l_, 16, 64);
        l_ += __shfl_xor(l_, 32, 64);
        float il = 1.0f / l_;
#pragma unroll
        for (int r = 0; r < 4; ++r) {
            float iv = __shfl(il, g * 4 + r, 64);
            int qrow = q0 + w * 16 + g * 4 + r;
#pragma unroll
            for (int d16 = 0; d16 < 4; ++d16) {
                int col = (h << 6) + d16 * 16 + li;
                ctxb[(size_t)qrow * DMODEL + col] = f2bf(o[d16][r] * iv);
            }
        }
        __syncthreads();   // pass 0's buffers free before pass 1 staging
    }
}

// ---------------------------------------------------------------------------
// LayerNorm over 768. BF=1 also emits bf16 copy.
// ---------------------------------------------------------------------------
template<int BF>
__global__ __launch_bounds__(256) void ln_kernel(const float* __restrict__ in,
    const float* __restrict__ gw, const float* __restrict__ bw,
    float* __restrict__ outf, u16* __restrict__ outb)
{
    __shared__ float red[8];
    const int row = blockIdx.x, tid = threadIdx.x;
    const float* x = in + (size_t)row * DMODEL;
    float v0 = x[tid], v1 = x[tid + 256], v2 = x[tid + 512];
    float s = v0 + v1 + v2;
#pragma unroll
    for (int off = 32; off > 0; off >>= 1) s += __shfl_xor(s, off, 64);
    const int wv = tid >> 6, lane = tid & 63;
    if (lane == 0) red[wv] = s;
    __syncthreads();
    float mu = (red[0] + red[1] + red[2] + red[3]) * (1.0f / DMODEL);
    float d0 = v0 - mu, d1 = v1 - mu, d2 = v2 - mu;
    float s2 = d0 * d0 + d1 * d1 + d2 * d2;
#pragma unroll
    for (int off = 32; off > 0; off >>= 1) s2 += __shfl_xor(s2, off, 64);
    if (lane == 0) red[4 + wv] = s2;
    __syncthreads();
    float var = (red[4] + red[5] + red[6] + red[7]) * (1.0f / DMODEL);
    float rstd = rsqrtf(var + 1e-5f);
    float y0 = d0 * rstd * gw[tid] + bw[tid];
    float y1 = d1 * rstd * gw[tid + 256] + bw[tid + 256];
    float y2 = d2 * rstd * gw[tid + 512] + bw[tid + 512];
    float* yo = outf + (size_t)row * DMODEL;
    yo[tid] = y0; yo[tid + 256] = y1; yo[tid + 512] = y2;
    if constexpr (BF) {
        u16* o = outb + (size_t)row * DMODEL;
        o[tid] = f2bf(y0); o[tid + 256] = f2bf(y1); o[tid + 512] = f2bf(y2);
    }
}

// ---------------------------------------------------------------------------
extern "C" void kernel_launch(void* const* d_in, const int* in_sizes, int n_in,
                              void* d_out, int out_size, void* d_ws, size_t ws_size,
                              hipStream_t stream)
{
    const float* x  = (const float*)d_in[0];
    const float* Wq = (const float*)d_in[1];  const float* bq = (const float*)d_in[2];
    const float* Wk = (const float*)d_in[3];  const float* bk = (const float*)d_in[4];
    const float* Wv = (const float*)d_in[5];  const float* bv = (const float*)d_in[6];
    const float* Wo = (const float*)d_in[7];  const float* bo = (const float*)d_in[8];
    const float* W1 = (const float*)d_in[9];  const float* b1 = (const float*)d_in[10];
    const float* W2 = (const float*)d_in[11]; const float* b2 = (const float*)d_in[12];
    const float* g1 = (const float*)d_in[13]; const float* be1 = (const float*)d_in[14];
    const float* g2 = (const float*)d_in[15]; const float* be2 = (const float*)d_in[16];
    float* out = (float*)d_out;

    char* wsb = (char*)d_ws;
    u16*   xb    = (u16*)(wsb + 0);
    u16*   Wqkvt = (u16*)(wsb + 6291456);
    u16*   Wot   = (u16*)(wsb + 9830400);
    u16*   W1t   = (u16*)(wsb + 11010048);
    u16*   W2t   = (u16*)(wsb + 15728640);
    float* bcat  = (float*)(wsb + 20447232);
    u16*   Qb    = (u16*)(wsb + 20456448);
    u16*   Kb2   = (u16*)(wsb + 26747904);
    u16*   VTb   = (u16*)(wsb + 33039360);
    u16*   ctxb  = (u16*)(wsb + 39330816);
    float* s1    = (float*)(wsb + 45622272);
    float* h     = (float*)(wsb + 58205184);
    u16*   hb    = (u16*)(wsb + 70788096);
    u16*   ff1b  = (u16*)(wsb + 77079552);
    float* t2    = (float*)(wsb + 102245376);

    tobf16<<<1024, 256, 0, stream>>>(x, xb, 786432);
    wtrans4<<<dim3(24, 24, 4), 256, 0, stream>>>(Wq, Wk, Wv, Wo, Wqkvt, Wot);
    wtrans<<<dim3(96, 24), 256, 0, stream>>>(W1, W1t, 768, 3072);
    wtrans<<<dim3(24, 96), 256, 0, stream>>>(W2, W2t, 3072, 768);
    bias_cat_kernel<<<9, 256, 0, stream>>>(bq, bk, bv, bcat);

    gemm_bf<128, 128, 0><<<dim3(18, 32), 256, 0, stream>>>(
        xb, Wqkvt, bcat, nullptr, nullptr, nullptr, Qb, Kb2, VTb, 2304, 768);
    attn64<<<384, 256, 0, stream>>>(Qb, Kb2, VTb, ctxb);
    gemm_bf<64, 128, 1><<<dim3(6, 64), 256, 0, stream>>>(
        ctxb, Wot, bo, x, s1, nullptr, nullptr, nullptr, nullptr, 768, 768);
    ln_kernel<1><<<4096, 256, 0, stream>>>(s1, g1, be1, h, hb);
    gemm_bf<128, 128, 2><<<dim3(24, 32), 256, 0, stream>>>(
        hb, W1t, b1, nullptr, nullptr, ff1b, nullptr, nullptr, nullptr, 3072, 768);
    gemm_bf<64, 128, 1><<<dim3(6, 64), 256, 0, stream>>>(
        ff1b, W2t, b2, h, t2, nullptr, nullptr, nullptr, nullptr, 768, 3072);
    ln_kernel<0><<<4096, 256, 0, stream>>>(t2, g2, be2, out, nullptr);
}

// Round 8
// 347.797 us; speedup vs baseline: 2.1798x; 1.0717x over previous
//
#include <hip/hip_runtime.h>
#include <math.h>

#define TSEQ 4096
#define DMODEL 768
#define NHEADS 12
#define DKH 64
#define DFF 3072
#define LOG2E 1.44269504f

typedef __attribute__((ext_vector_type(4))) float f32x4;
typedef __attribute__((ext_vector_type(8))) short s16x8;
typedef unsigned short u16;
typedef unsigned int u32;

__device__ __forceinline__ u16 f2bf(float x) {
    u32 u = __builtin_bit_cast(u32, x);
    u32 r = u + 0x7FFFu + ((u >> 16) & 1u);
    return (u16)(r >> 16);
}
__device__ __forceinline__ float bf2f(u16 h) {
    u32 u = ((u32)h) << 16;
    return __builtin_bit_cast(float, u);
}
__device__ __forceinline__ u32 cvtpk(float lo, float hi) {
    u32 r;
    asm("v_cvt_pk_bf16_f32 %0, %1, %2" : "=v"(r) : "v"(lo), "v"(hi));
    return r;
}

__device__ __forceinline__ void gll16(const void* g, void* lds) {
    __builtin_amdgcn_global_load_lds(
        (const __attribute__((address_space(1))) u32*)g,
        (__attribute__((address_space(3))) u32*)lds, 16, 0, 0);
}

// ---------------------------------------------------------------------------
// f32 -> bf16 cast, vectorized.
// ---------------------------------------------------------------------------
__global__ __launch_bounds__(256) void tobf16(const float* __restrict__ in,
                                              u16* __restrict__ out, int n4)
{
    int idx = blockIdx.x * 256 + threadIdx.x;
    for (int i = idx; i < n4; i += 262144) {
        float4 v = *(const float4*)(in + (size_t)i * 4);
        *(ushort4*)(out + (size_t)i * 4) =
            make_ushort4(f2bf(v.x), f2bf(v.y), f2bf(v.z), f2bf(v.w));
    }
}

// ---------------------------------------------------------------------------
// Transpose W [768][768] f32 -> bf16 B^T rows. z selects Wq/Wk/Wv/Wo.
// ---------------------------------------------------------------------------
__global__ __launch_bounds__(256) void wtrans4(
    const float* __restrict__ Wq, const float* __restrict__ Wk,
    const float* __restrict__ Wv, const float* __restrict__ Wo,
    u16* __restrict__ Wqkvt, u16* __restrict__ Wot)
{
    __shared__ float t[32 * 33];
    const int z = blockIdx.z;
    const float* W = (z == 0) ? Wq : (z == 1) ? Wk : (z == 2) ? Wv : Wo;
    u16* out = (z < 3) ? Wqkvt : Wot;
    const int nofs = (z < 3) ? z * 768 : 0;
    const int K = 768, N = 768;
    const int tid = threadIdx.x;
    const int kt = blockIdx.y << 5, nt = blockIdx.x << 5;
    const int r = tid >> 3, c4 = tid & 7;
    float4 v = *(const float4*)(W + (size_t)(kt + r) * N + nt + (c4 << 2));
    t[r * 33 + (c4 << 2) + 0] = v.x;
    t[r * 33 + (c4 << 2) + 1] = v.y;
    t[r * 33 + (c4 << 2) + 2] = v.z;
    t[r * 33 + (c4 << 2) + 3] = v.w;
    __syncthreads();
    float a0 = t[((c4 << 2) + 0) * 33 + r];
    float a1 = t[((c4 << 2) + 1) * 33 + r];
    float a2 = t[((c4 << 2) + 2) * 33 + r];
    float a3 = t[((c4 << 2) + 3) * 33 + r];
    u16* o = out + (size_t)(nofs + nt + r) * K + kt + (c4 << 2);
    *(ushort4*)o = make_ushort4(f2bf(a0), f2bf(a1), f2bf(a2), f2bf(a3));
}

__global__ __launch_bounds__(256) void wtrans(const float* __restrict__ W,
                                              u16* __restrict__ out,
                                              int K, int N)
{
    __shared__ float t[32 * 33];
    const int tid = threadIdx.x;
    const int kt = blockIdx.y << 5, nt = blockIdx.x << 5;
    const int r = tid >> 3, c4 = tid & 7;
    float4 v = *(const float4*)(W + (size_t)(kt + r) * N + nt + (c4 << 2));
    t[r * 33 + (c4 << 2) + 0] = v.x;
    t[r * 33 + (c4 << 2) + 1] = v.y;
    t[r * 33 + (c4 << 2) + 2] = v.z;
    t[r * 33 + (c4 << 2) + 3] = v.w;
    __syncthreads();
    float a0 = t[((c4 << 2) + 0) * 33 + r];
    float a1 = t[((c4 << 2) + 1) * 33 + r];
    float a2 = t[((c4 << 2) + 2) * 33 + r];
    float a3 = t[((c4 << 2) + 3) * 33 + r];
    u16* o = out + (size_t)(nt + r) * K + kt + (c4 << 2);
    *(ushort4*)o = make_ushort4(f2bf(a0), f2bf(a1), f2bf(a2), f2bf(a3));
}

__global__ __launch_bounds__(256) void bias_cat_kernel(const float* bq, const float* bk,
                                                       const float* bv, float* o)
{
    int i = blockIdx.x * 256 + threadIdx.x;
    if (i < 768) o[i] = bq[i];
    else if (i < 1536) o[i] = bk[i - 768];
    else if (i < 2304) o[i] = bv[i - 1536];
}

// ---------------------------------------------------------------------------
// bf16 MFMA GEMM. A[M][KP], B^T[N][KP] bf16. BK=64, 4 waves.
// LDS XOR-swizzle (pre-swizzled global source, swizzled read). XCD remap.
// EPI 0: QKV (Q scaled by 0.125*log2e; Q/K head-major bf16; V^T bf16)
// EPI 1: f32 out = acc + bias + R
// EPI 2: relu(acc+bias) -> bf16 store, pitch N
// ---------------------------------------------------------------------------
template<int BM, int BN, int EPI>
__global__ __launch_bounds__(256) void gemm_bf(
    const u16* __restrict__ A, const u16* __restrict__ B,
    const float* __restrict__ bias, const float* __restrict__ R,
    float* __restrict__ Cf, u16* __restrict__ Cs,
    u16* __restrict__ Qb, u16* __restrict__ Kb, u16* __restrict__ VTb,
    int N, int KP)
{
    constexpr int FM = BM / 32, FN = BN / 32, NC = BN / 2, NCP = NC + 4;
    __shared__ u16 As[BM * 64];
    __shared__ u16 Bs[BN * 64];
    __shared__ float Ep[4 * 16 * NCP];

    const int tid = threadIdx.x;
    const int w = tid >> 6, lane = tid & 63;
    const int wr = w >> 1, wc = w & 1;
    const int li = lane & 15, g = lane >> 4;

    const int gX = gridDim.x;
    const int nwg = gridDim.x * gridDim.y;
    const int wid = blockIdx.y * gX + blockIdx.x;
    const int qc = nwg >> 3;
    const int nid = (wid & 7) * qc + (wid >> 3);
    const int m0 = (nid / gX) * BM, n0 = (nid % gX) * BN;

    f32x4 acc[FM][FN];
#pragma unroll
    for (int mi = 0; mi < FM; ++mi)
#pragma unroll
        for (int ni = 0; ni < FN; ++ni) acc[mi][ni] = (f32x4){0.f, 0.f, 0.f, 0.f};

    const int row8 = lane >> 3;
    const int cs = (lane & 7) ^ row8;
    const int l7 = li & 7;

    for (int k0 = 0; k0 < KP; k0 += 64) {
        __syncthreads();
#pragma unroll
        for (int i = 0; i < BM / 32; ++i) {
            int inst = w * (BM / 32) + i;
            const u16* gp = A + (size_t)(m0 + inst * 8 + row8) * KP + k0 + cs * 8;
            gll16(gp, &As[inst * 512]);
        }
#pragma unroll
        for (int i = 0; i < BN / 32; ++i) {
            int inst = w * (BN / 32) + i;
            const u16* gp = B + (size_t)(n0 + inst * 8 + row8) * KP + k0 + cs * 8;
            gll16(gp, &Bs[inst * 512]);
        }
        __syncthreads();
        s16x8 af[FM][2], bfr[FN][2];
#pragma unroll
        for (int mi = 0; mi < FM; ++mi) {
            int Ra = wr * (BM / 2) + mi * 16 + li;
#pragma unroll
            for (int dc = 0; dc < 2; ++dc)
                af[mi][dc] = *(const s16x8*)&As[Ra * 64 + ((dc * 4 + g) ^ l7) * 8];
        }
#pragma unroll
        for (int ni = 0; ni < FN; ++ni) {
            int Rb = wc * (BN / 2) + ni * 16 + li;
#pragma unroll
            for (int dc = 0; dc < 2; ++dc)
                bfr[ni][dc] = *(const s16x8*)&Bs[Rb * 64 + ((dc * 4 + g) ^ l7) * 8];
        }
        __builtin_amdgcn_s_setprio(1);
#pragma unroll
        for (int mi = 0; mi < FM; ++mi)
#pragma unroll
            for (int ni = 0; ni < FN; ++ni) {
                acc[mi][ni] = __builtin_amdgcn_mfma_f32_16x16x32_bf16(
                    af[mi][0], bfr[ni][0], acc[mi][ni], 0, 0, 0);
                acc[mi][ni] = __builtin_amdgcn_mfma_f32_16x16x32_bf16(
                    af[mi][1], bfr[ni][1], acc[mi][ni], 0, 0, 0);
            }
        __builtin_amdgcn_s_setprio(0);
    }
    __syncthreads();

    float* ep = Ep + w * 16 * NCP;
    const int colbase = n0 + wc * NC;
    const int rr = lane >> 2, ch = lane & 3;

#pragma unroll
    for (int mi = 0; mi < FM; ++mi) {
#pragma unroll
        for (int ni = 0; ni < FN; ++ni)
#pragma unroll
            for (int r = 0; r < 4; ++r)
                ep[(g * 4 + r) * NCP + ni * 16 + li] = acc[mi][ni][r];
        asm volatile("s_waitcnt lgkmcnt(0)" ::: "memory");

        const int grow0 = m0 + wr * (BM / 2) + mi * 16;
        const int grow = grow0 + rr;

        if constexpr (EPI == 1) {
#pragma unroll
            for (int q = 0; q < NC / 16; ++q) {
                int col = ch * (NC / 4) + q * 4;
                f32x4 v = *(f32x4*)&ep[rr * NCP + col];
                int gn = colbase + col;
                float4 bb = *(const float4*)(bias + gn);
                float4 rv = *(const float4*)(R + (size_t)grow * N + gn);
                float4 ov;
                ov.x = v[0] + bb.x + rv.x; ov.y = v[1] + bb.y + rv.y;
                ov.z = v[2] + bb.z + rv.z; ov.w = v[3] + bb.w + rv.w;
                *(float4*)(Cf + (size_t)grow * N + gn) = ov;
            }
        } else if constexpr (EPI == 2) {
#pragma unroll
            for (int q = 0; q < NC / 16; ++q) {
                int col = ch * (NC / 4) + q * 4;
                f32x4 v = *(f32x4*)&ep[rr * NCP + col];
                int gn = colbase + col;
                float4 bb = *(const float4*)(bias + gn);
                float x0 = fmaxf(v[0] + bb.x, 0.f), x1 = fmaxf(v[1] + bb.y, 0.f);
                float x2 = fmaxf(v[2] + bb.z, 0.f), x3 = fmaxf(v[3] + bb.w, 0.f);
                *(ushort4*)(Cs + (size_t)grow * N + gn) =
                    make_ushort4(f2bf(x0), f2bf(x1), f2bf(x2), f2bf(x3));
            }
        } else {  // EPI 0: QKV
            const int seg = colbase / 768;
            const int hh = (colbase % 768) >> 6;
            if (seg < 2) {
                u16* dst = (seg == 0) ? Qb : Kb;
                const float sc2 = (seg == 0) ? 0.125f * LOG2E : 1.0f;
#pragma unroll
                for (int q = 0; q < NC / 16; ++q) {
                    int col = ch * (NC / 4) + q * 4;
                    f32x4 v = *(f32x4*)&ep[rr * NCP + col];
                    float4 bb = *(const float4*)(bias + colbase + col);
                    u16 h0 = f2bf((v[0] + bb.x) * sc2);
                    u16 h1 = f2bf((v[1] + bb.y) * sc2);
                    u16 h2 = f2bf((v[2] + bb.z) * sc2);
                    u16 h3 = f2bf((v[3] + bb.w) * sc2);
                    *(ushort4*)&dst[((size_t)(hh << 12) + grow) * 64 + col] =
                        make_ushort4(h0, h1, h2, h3);
                }
            } else {
                float bb = bias[colbase + lane];
                s16x8 pa, pb;
#pragma unroll
                for (int r2 = 0; r2 < 8; ++r2)
                    pa[r2] = (short)f2bf(ep[r2 * NCP + lane] + bb);
#pragma unroll
                for (int r2 = 0; r2 < 8; ++r2)
                    pb[r2] = (short)f2bf(ep[(8 + r2) * NCP + lane] + bb);
                u16* ov = VTb + ((size_t)(hh << 6) + lane) * TSEQ + grow0;
                *(s16x8*)(ov)     = pa;
                *(s16x8*)(ov + 8) = pb;
            }
        }
    }
}

// ---------------------------------------------------------------------------
// Split-K flash attention, bf16 MFMA, causal. Block = (head, pair {p,63-p},
// k-split half). Low split: k-tiles [0, ceil(nk/2)); high: [ceil(nk/2), nk).
// ~32-33 k-tiles per block, 768 uniform blocks, all co-resident (12 waves/CU).
// Writes unnormalized O_part + per-row (m, l); combine kernel merges.
// Head-grouped XCD mapping keeps K/V L2-resident (round-7 result: 10.8MB fetch).
// ---------------------------------------------------------------------------
__global__ __launch_bounds__(256) void attn64sp(
    const u16* __restrict__ Qb, const u16* __restrict__ Kb,
    const u16* __restrict__ VTb, float* __restrict__ Opart,
    float* __restrict__ Mp, float* __restrict__ Lp)
{
    __shared__ u16 Ks[2][4096];   // [64 tok][64 d], 8 swizzle slots/row
    __shared__ u16 Vs[2][4096];   // V^T [64 d][64 tok]
    __shared__ u16 Ps[4][1024];   // per-wave P [16 q][64 k]

    const int tid = threadIdx.x, w = tid >> 6, lane = tid & 63;
    const int g = lane >> 4, li = lane & 15, l7 = lane & 7;
    const int wid = blockIdx.x;
    const int nid = (wid & 7) * 96 + (wid >> 3);   // head-grouped XCD mapping
    const int h = nid >> 6;
    const int rest = nid & 63;
    const int p = rest & 31;
    const int split = rest >> 5;

    const u16* Qh = Qb + ((size_t)h << 18);
    const u16* Kh = Kb + ((size_t)h << 18);
    const u16* Vh = VTb + ((size_t)h << 18);

    const int row8 = lane >> 3;
    const int cs = (lane & 7) ^ row8;

    for (int pass = 0; pass < 2; ++pass) {
        const int qbk = pass ? 63 - p : p;
        const int q0 = qbk << 6;
        const int nkf = qbk + 1;
        const int half = (nkf + 1) >> 1;
        const int kb0 = split ? half : 0;
        const int kbe = split ? nkf : half;

        s16x8 qf[2];
#pragma unroll
        for (int dc = 0; dc < 2; ++dc)
            qf[dc] = *(const s16x8*)(Qh + (size_t)(q0 + w * 16 + li) * 64 + dc * 32 + g * 8);

        const u16* kbase = Kh + (size_t)(w * 16 + row8) * 64 + cs * 8;
        const u16* vbase = Vh + (size_t)(w * 16 + row8) * TSEQ + cs * 8;

        f32x4 o[4];
        float m_ = -1e30f, l_ = 0.f;
#pragma unroll
        for (int d16 = 0; d16 < 4; ++d16) o[d16] = (f32x4){0.f, 0.f, 0.f, 0.f};

        if (kb0 < kbe) {
            // prologue: stage tile kb0 into buffer 0
#pragma unroll
            for (int i = 0; i < 2; ++i) {
                int inst = w * 2 + i;
                gll16(kbase + (size_t)kb0 * 4096 + (size_t)i * 512, &Ks[0][inst * 512]);
                gll16(vbase + (size_t)kb0 * 64 + (size_t)i * 8 * TSEQ, &Vs[0][inst * 512]);
            }
            __syncthreads();

            for (int kb = kb0; kb < kbe; ++kb) {
                const int cur = (kb - kb0) & 1;
                if (kb + 1 < kbe) {
                    const int kn = kb + 1;
#pragma unroll
                    for (int i = 0; i < 2; ++i) {
                        int inst = w * 2 + i;
                        gll16(kbase + (size_t)kn * 4096 + (size_t)i * 512, &Ks[cur ^ 1][inst * 512]);
                        gll16(vbase + (size_t)kn * 64 + (size_t)i * 8 * TSEQ, &Vs[cur ^ 1][inst * 512]);
                    }
                }

                // QK^T swapped: s[c] rows k = c*16+g*4+r, col q = li
                f32x4 s[4];
                __builtin_amdgcn_s_setprio(1);
#pragma unroll
                for (int c = 0; c < 4; ++c) {
                    s[c] = (f32x4){0.f, 0.f, 0.f, 0.f};
                    s16x8 a0 = *(const s16x8*)&Ks[cur][(c * 16 + li) * 64 + ((g) ^ l7) * 8];
                    s16x8 a1 = *(const s16x8*)&Ks[cur][(c * 16 + li) * 64 + ((4 + g) ^ l7) * 8];
                    s[c] = __builtin_amdgcn_mfma_f32_16x16x32_bf16(a0, qf[0], s[c], 0, 0, 0);
                    s[c] = __builtin_amdgcn_mfma_f32_16x16x32_bf16(a1, qf[1], s[c], 0, 0, 0);
                }
                __builtin_amdgcn_s_setprio(0);

                if (kb == qbk) {   // diagonal tile mask
#pragma unroll
                    for (int c = 0; c < 4; ++c)
#pragma unroll
                        for (int r = 0; r < 4; ++r) {
                            int kglob = (kb << 6) + c * 16 + g * 4 + r;
                            int qglob = q0 + w * 16 + li;
                            if (kglob > qglob) s[c][r] = -1e30f;
                        }
                }

                // per-lane PARTIAL max (no cross-lane in steady state)
                float v0 = fmaxf(fmaxf(s[0][0], s[0][1]), fmaxf(s[0][2], s[0][3]));
                float v1 = fmaxf(fmaxf(s[1][0], s[1][1]), fmaxf(s[1][2], s[1][3]));
                float v2 = fmaxf(fmaxf(s[2][0], s[2][1]), fmaxf(s[2][2], s[2][3]));
                float v3 = fmaxf(fmaxf(s[3][0], s[3][1]), fmaxf(s[3][2], s[3][3]));
                float pmp = fmaxf(fmaxf(v0, v1), fmaxf(v2, v3));

                if (!__all(pmp <= m_ + 8.f)) {
                    float pm = fmaxf(pmp, __shfl_xor(pmp, 16, 64));
                    pm = fmaxf(pm, __shfl_xor(pm, 32, 64));
                    float mn = fmaxf(m_, pm);
                    float sc2 = exp2f(m_ - mn);
                    m_ = mn;
                    l_ *= sc2;
#pragma unroll
                    for (int r = 0; r < 4; ++r) {
                        float os = __shfl(sc2, g * 4 + r, 64);
#pragma unroll
                        for (int d16 = 0; d16 < 4; ++d16) o[d16][r] *= os;
                    }
                }

#pragma unroll
                for (int c = 0; c < 4; ++c) {
                    float e0 = exp2f(s[c][0] - m_);
                    float e1 = exp2f(s[c][1] - m_);
                    float e2 = exp2f(s[c][2] - m_);
                    float e3 = exp2f(s[c][3] - m_);
                    l_ += (e0 + e1) + (e2 + e3);
                    u32 r0 = cvtpk(e0, e1);
                    u32 r1 = cvtpk(e2, e3);
                    *(uint2*)&Ps[w][li * 64 + ((c * 16 + 4 * g) ^ (l7 << 3))] =
                        make_uint2(r0, r1);
                }

                asm volatile("s_waitcnt lgkmcnt(0)" ::: "memory");
                __builtin_amdgcn_sched_barrier(0);

                __builtin_amdgcn_s_setprio(1);
#pragma unroll
                for (int ks = 0; ks < 2; ++ks) {
                    int koff = ((ks * 4 + g) ^ l7) * 8;
                    s16x8 pf = *(const s16x8*)&Ps[w][li * 64 + ((ks * 32 + g * 8) ^ (l7 << 3))];
#pragma unroll
                    for (int d16 = 0; d16 < 4; ++d16) {
                        s16x8 vf = *(const s16x8*)&Vs[cur][(d16 * 16 + li) * 64 + koff];
                        o[d16] = __builtin_amdgcn_mfma_f32_16x16x32_bf16(pf, vf, o[d16], 0, 0, 0);
                    }
                }
                __builtin_amdgcn_s_setprio(0);
                __syncthreads();
            }
        }

        // epilogue: combine per-lane l_ partials across g; write partials
        l_ += __shfl_xor(l_, 16, 64);
        l_ += __shfl_xor(l_, 32, 64);
        float* ob = Opart + (size_t)split * (TSEQ * DMODEL);
#pragma unroll
        for (int r = 0; r < 4; ++r) {
            int qrow = q0 + w * 16 + g * 4 + r;
#pragma unroll
            for (int d16 = 0; d16 < 4; ++d16) {
                int col = (h << 6) + d16 * 16 + li;
                ob[(size_t)qrow * DMODEL + col] = o[d16][r];
            }
        }
        if (g == 0) {
            int qrow = q0 + w * 16 + li;
            Mp[(size_t)(split * NHEADS + h) * TSEQ + qrow] = m_;
            Lp[(size_t)(split * NHEADS + h) * TSEQ + qrow] = l_;
        }
    }
}

// ---------------------------------------------------------------------------
// Combine the two split-K partials: ctx = (w0*O0 + w1*O1)/(w0*l0 + w1*l1),
// w_i = exp2(m_i - max(m0,m1)). Memory-bound, ~50MB.
// ---------------------------------------------------------------------------
__global__ __launch_bounds__(256) void attn_combine(
    const float* __restrict__ Opart, const float* __restrict__ Mp,
    const float* __restrict__ Lp, u16* __restrict__ ctxb)
{
    int idx = blockIdx.x * 256 + threadIdx.x;     // 786432 float4 chunks
    int row = idx / 192;
    int c4 = (idx - row * 192) << 2;
    int h = c4 >> 6;
    float m0 = Mp[(size_t)h * TSEQ + row];
    float m1 = Mp[(size_t)(NHEADS + h) * TSEQ + row];
    float l0 = Lp[(size_t)h * TSEQ + row];
    float l1 = Lp[(size_t)(NHEADS + h) * TSEQ + row];
    float M = fmaxf(m0, m1);
    float w0 = exp2f(m0 - M), w1 = exp2f(m1 - M);
    float iL = 1.0f / (w0 * l0 + w1 * l1);
    float4 a = *(const float4*)(Opart + (size_t)row * DMODEL + c4);
    float4 b = *(const float4*)(Opart + (size_t)(TSEQ * DMODEL) + (size_t)row * DMODEL + c4);
    float x0 = (w0 * a.x + w1 * b.x) * iL;
    float x1 = (w0 * a.y + w1 * b.y) * iL;
    float x2 = (w0 * a.z + w1 * b.z) * iL;
    float x3 = (w0 * a.w + w1 * b.w) * iL;
    *(ushort4*)(ctxb + (size_t)row * DMODEL + c4) =
        make_ushort4(f2bf(x0), f2bf(x1), f2bf(x2), f2bf(x3));
}

// ---------------------------------------------------------------------------
// LayerNorm over 768. BF=1 also emits bf16 copy.
// ---------------------------------------------------------------------------
template<int BF>
__global__ __launch_bounds__(256) void ln_kernel(const float* __restrict__ in,
    const float* __restrict__ gw, const float* __restrict__ bw,
    float* __restrict__ outf, u16* __restrict__ outb)
{
    __shared__ float red[8];
    const int row = blockIdx.x, tid = threadIdx.x;
    const float* x = in + (size_t)row * DMODEL;
    float v0 = x[tid], v1 = x[tid + 256], v2 = x[tid + 512];
    float s = v0 + v1 + v2;
#pragma unroll
    for (int off = 32; off > 0; off >>= 1) s += __shfl_xor(s, off, 64);
    const int wv = tid >> 6, lane = tid & 63;
    if (lane == 0) red[wv] = s;
    __syncthreads();
    float mu = (red[0] + red[1] + red[2] + red[3]) * (1.0f / DMODEL);
    float d0 = v0 - mu, d1 = v1 - mu, d2 = v2 - mu;
    float s2 = d0 * d0 + d1 * d1 + d2 * d2;
#pragma unroll
    for (int off = 32; off > 0; off >>= 1) s2 += __shfl_xor(s2, off, 64);
    if (lane == 0) red[4 + wv] = s2;
    __syncthreads();
    float var = (red[4] + red[5] + red[6] + red[7]) * (1.0f / DMODEL);
    float rstd = rsqrtf(var + 1e-5f);
    float y0 = d0 * rstd * gw[tid] + bw[tid];
    float y1 = d1 * rstd * gw[tid + 256] + bw[tid + 256];
    float y2 = d2 * rstd * gw[tid + 512] + bw[tid + 512];
    float* yo = outf + (size_t)row * DMODEL;
    yo[tid] = y0; yo[tid + 256] = y1; yo[tid + 512] = y2;
    if constexpr (BF) {
        u16* o = outb + (size_t)row * DMODEL;
        o[tid] = f2bf(y0); o[tid + 256] = f2bf(y1); o[tid + 512] = f2bf(y2);
    }
}

// ---------------------------------------------------------------------------
// Workspace (bytes):
//  xb@0 | Wqkvt@6291456 | Wot@9830400 | W1t@11010048 | W2t@15728640
//  bcat@20447232 | Qb@20456448 | Kb@26747904 | VTb@33039360 | ctxb@39330816
//  s1@45622272 | h@58205184 | hb@70788096 | ff1b@77079552 | t2@102245376
//  Opart@45622272 (aliases s1+h, dead during attn) 25.2MB
//  Mp@70788096, Lp@71181312 (alias hb region, dead during attn)
// ---------------------------------------------------------------------------
extern "C" void kernel_launch(void* const* d_in, const int* in_sizes, int n_in,
                              void* d_out, int out_size, void* d_ws, size_t ws_size,
                              hipStream_t stream)
{
    const float* x  = (const float*)d_in[0];
    const float* Wq = (const float*)d_in[1];  const float* bq = (const float*)d_in[2];
    const float* Wk = (const float*)d_in[3];  const float* bk = (const float*)d_in[4];
    const float* Wv = (const float*)d_in[5];  const float* bv = (const float*)d_in[6];
    const float* Wo = (const float*)d_in[7];  const float* bo = (const float*)d_in[8];
    const float* W1 = (const float*)d_in[9];  const float* b1 = (const float*)d_in[10];
    const float* W2 = (const float*)d_in[11]; const float* b2 = (const float*)d_in[12];
    const float* g1 = (const float*)d_in[13]; const float* be1 = (const float*)d_in[14];
    const float* g2 = (const float*)d_in[15]; const float* be2 = (const float*)d_in[16];
    float* out = (float*)d_out;

    char* wsb = (char*)d_ws;
    u16*   xb    = (u16*)(wsb + 0);
    u16*   Wqkvt = (u16*)(wsb + 6291456);
    u16*   Wot   = (u16*)(wsb + 9830400);
    u16*   W1t   = (u16*)(wsb + 11010048);
    u16*   W2t   = (u16*)(wsb + 15728640);
    float* bcat  = (float*)(wsb + 20447232);
    u16*   Qb    = (u16*)(wsb + 20456448);
    u16*   Kb2   = (u16*)(wsb + 26747904);
    u16*   VTb   = (u16*)(wsb + 33039360);
    u16*   ctxb  = (u16*)(wsb + 39330816);
    float* s1    = (float*)(wsb + 45622272);
    float* h     = (float*)(wsb + 58205184);
    u16*   hb    = (u16*)(wsb + 70788096);
    u16*   ff1b  = (u16*)(wsb + 77079552);
    float* t2    = (float*)(wsb + 102245376);
    float* Opart = (float*)(wsb + 45622272);   // aliases s1+h (dead during attn)
    float* Mp    = (float*)(wsb + 70788096);   // aliases hb (dead during attn)
    float* Lp    = (float*)(wsb + 71181312);

    tobf16<<<1024, 256, 0, stream>>>(x, xb, 786432);
    wtrans4<<<dim3(24, 24, 4), 256, 0, stream>>>(Wq, Wk, Wv, Wo, Wqkvt, Wot);
    wtrans<<<dim3(96, 24), 256, 0, stream>>>(W1, W1t, 768, 3072);
    wtrans<<<dim3(24, 96), 256, 0, stream>>>(W2, W2t, 3072, 768);
    bias_cat_kernel<<<9, 256, 0, stream>>>(bq, bk, bv, bcat);

    gemm_bf<128, 128, 0><<<dim3(18, 32), 256, 0, stream>>>(
        xb, Wqkvt, bcat, nullptr, nullptr, nullptr, Qb, Kb2, VTb, 2304, 768);
    attn64sp<<<768, 256, 0, stream>>>(Qb, Kb2, VTb, Opart, Mp, Lp);
    attn_combine<<<3072, 256, 0, stream>>>(Opart, Mp, Lp, ctxb);
    gemm_bf<64, 128, 1><<<dim3(6, 64), 256, 0, stream>>>(
        ctxb, Wot, bo, x, s1, nullptr, nullptr, nullptr, nullptr, 768, 768);
    ln_kernel<1><<<4096, 256, 0, stream>>>(s1, g1, be1, h, hb);
    gemm_bf<128, 128, 2><<<dim3(24, 32), 256, 0, stream>>>(
        hb, W1t, b1, nullptr, nullptr, ff1b, nullptr, nullptr, nullptr, 3072, 768);
    gemm_bf<64, 128, 1><<<dim3(6, 64), 256, 0, stream>>>(
        ff1b, W2t, b2, h, t2, nullptr, nullptr, nullptr, nullptr, 768, 3072);
    ln_kernel<0><<<4096, 256, 0, stream>>>(t2, g2, be2, out, nullptr);
}